// Round 11
// baseline (819.262 us; speedup 1.0000x reference)
//
#include <hip/hip_runtime.h>
#include <hip/hip_bf16.h>

// MonetMoVDE: B=4 T=2048 D=2048 H=8 E=512 M=8, F=4096, HALF=1024
#define TOK   8192   // B*T
#define DD    2048
#define FF    4096
#define EE    512
#define HALF  1024
#define KCAT  8704   // F + F + E  (concat K for V-GEMMs, 8704 = 136*64)

typedef __bf16 bf16x8 __attribute__((ext_vector_type(8)));
typedef __bf16 bf16x4 __attribute__((ext_vector_type(4)));
typedef float  f32x4  __attribute__((ext_vector_type(4)));
using bf16 = __hip_bfloat16;

#define AS1(p) ((const __attribute__((address_space(1))) void*)(p))
#define AS3(p) ((__attribute__((address_space(3))) void*)(p))

// ---------------- prep kernels ----------------

__global__ void cvt_bf16(const float* __restrict__ in, bf16* __restrict__ out, int n4) {
    int i = blockIdx.x * blockDim.x + threadIdx.x;
    int stride = gridDim.x * blockDim.x;
    for (; i < n4; i += stride) {
        float4 v = ((const float4*)in)[i];
        bf16x4 o;
        o[0] = (__bf16)v.x; o[1] = (__bf16)v.y; o[2] = (__bf16)v.z; o[3] = (__bf16)v.w;
        ((bf16x4*)out)[i] = o;
    }
}

// bmat tails: Wl[n][8192+e] = b1[e][n]; Wr likewise (bT part of the concat-K weights)
__global__ void pack_b(const float* __restrict__ b1, const float* __restrict__ b2,
                       bf16* __restrict__ Wl, bf16* __restrict__ Wr) {
    int n = blockIdx.x;
    for (int e = threadIdx.x; e < EE; e += 256) {
        Wl[(long)n * KCAT + 2 * FF + e] = __float2bfloat16(b1[(long)e * HALF + n]);
        Wr[(long)n * KCAT + 2 * FF + e] = __float2bfloat16(b2[(long)e * HALF + n]);
    }
}

// ---------------- GEMM: C[m,n] = sum_k A[m,k] * Bw[n,k] ----------------
// r6-exact structure (best verified: 46% MfmaUtil, 0 bank conflicts).
// 256x256 tile, BK=64, 8 waves (2Mx4N), 16x16x32 MFMA, per-wave C 128x64.
// LDS buffer (64KB) = 4 planes of 16KB: A_k0 @0, A_k1 @16K, B_k0 @32K, B_k1 @48K.
// Plane = 256 rows x 64B, swizzle byte ^= (((row>>1)&3)<<4) - proven zero-conflict.
// REGISTER-PIPELINED phases: each phase {[aux store/load]; stage 2 chunk-gloads;
// [vmcnt]; barrier; ds_read NEXT phase's frags; MFMA on frags read LAST phase}.
// AUX (MODE 1 only): per phase 1 global store (prev slice, f32->bf16x4) + 1
// global load (float4) issued BEFORE the stage loads; FIFO: at each vmcnt(4)
// gate, outstanding = prev-stages(4)+aux(2)+cur-stages(4) -> gate retires
// prev-stages AND aux, leaving cur-stages. Ledger intact; aux never gated hot.
// Aux slices: sid = blockIdx.x*2*nt + t*2 + ph; sid<32768: g1|g2 f32->bf16 into
// Yl[t][FF..2FF) / Yr[t][0..FF) (y12/y21 slots, overwritten later by glue);
// 32768<=sid<40960: v11|v12|v21|v22 -> Wl/Wr pack.
// Fused dual-GEMM; MODE 0: fp32 store, MODE 1: relu(z+bias)^2 -> bf16 store.
template<int MODE>
__global__ __launch_bounds__(512, 2)
void gemmP(const bf16* __restrict__ A0, const bf16* __restrict__ B0,
           const float* __restrict__ bias0, void* __restrict__ C0,
           const bf16* __restrict__ A1, const bf16* __restrict__ B1,
           const float* __restrict__ bias1, void* __restrict__ C1,
           int nbm, int nbn, int K, int ldc,
           const float* __restrict__ xg1, const float* __restrict__ xg2,
           const float* __restrict__ xv11, const float* __restrict__ xv12,
           const float* __restrict__ xv21, const float* __restrict__ xv22,
           bf16* __restrict__ xYl, bf16* __restrict__ xYr,
           bf16* __restrict__ xWl, bf16* __restrict__ xWr)
{
    __shared__ __align__(16) char smem[131072];   // 2 x 64KB
    const int tid  = threadIdx.x;
    const int lane = tid & 63;
    const int wid  = tid >> 6;
    const int wm = wid >> 2, wn = wid & 3;
    const int r16 = lane & 15, kb = lane >> 4;

    int bid = blockIdx.x;
    {   // bijective XCD swizzle (m204)
        int nwg = gridDim.x;
        int q = nwg >> 3, r = nwg & 7;
        int xcd = bid & 7, idx = bid >> 3;
        bid = (xcd < r ? xcd * (q + 1) : r * (q + 1) + (xcd - r) * q) + idx;
    }
    const int npg = nbm * nbn;
    const int g   = bid / npg;
    const int lb  = bid - g * npg;
    const int bm = lb / nbn, bn = lb - bm * nbn;

    const bf16*  A    = g ? A1 : A0;
    const bf16*  Bw   = g ? B1 : B0;
    const float* bias = g ? bias1 : bias0;
    char* Cout = (char*)(g ? C1 : C0);

    const long row0 = (long)bm * 256;
    const int  col0 = bn * 256;
    const int  nt   = K >> 6;

    // staging sources (pre-swizzled; involution) + linear LDS dest offset
    const char* gA[2]; const char* gB[2];
    #pragma unroll
    for (int l = 0; l < 2; ++l) {
        const uint32_t S = (uint32_t)(l * 512 + tid) * 16;   // byte slot in 16KB plane
        const int r  = (int)(S >> 6);                        // plane row 0..255
        const int cb = (int)((S & 63) ^ ((uint32_t)((r >> 1) & 3) << 4));
        gA[l] = (const char*)A  + (row0 + r) * (long)K * 2 + cb;
        gB[l] = (const char*)Bw + (long)(col0 + r) * K * 2 + cb;
    }
    const uint32_t ldst = (uint32_t)(tid & ~63) * 16;        // + l*8192 + plane base

    // per-lane read base offsets within a plane (swizzled; proven zero-conflict)
    const uint32_t swz  = ((uint32_t)(r16 >> 1) & 3u) << 4;
    const uint32_t aoff = (uint32_t)((wm * 128 + r16) * 64 + kb * 16) ^ swz;  // +4096 for row-half1, +fi*1024
    const uint32_t boff = (uint32_t)((wn * 64  + r16) * 64 + kb * 16) ^ swz;  // +fj*1024

    // ---- aux state (MODE 1 only) ----
    const int auxBase = (MODE == 1) ? blockIdx.x * (2 * nt) : 0x7fffffff;
    float4 auxData = {0.f, 0.f, 0.f, 0.f};
    bf16*  auxDst  = nullptr;
    auto aux_calc = [&](int sid, const float*& src, bf16*& dst) {
        long F = ((long)sid << 11) + tid * 4;
        if (sid < 32768) {
            const long TG = (long)TOK * FF;
            if (F < TG) { long tt = F >> 12, j = F & 4095; src = xg1 + F;      dst = xYl + tt * KCAT + FF + j; }
            else { long F2 = F - TG; long tt = F2 >> 12, j = F2 & 4095; src = xg2 + F2; dst = xYr + tt * KCAT + j; }
        } else {
            long F2 = F - (((long)32768) << 11);
            const long SEG = (long)HALF * FF;
            int which = (F2 >= 3 * SEG) ? 3 : (F2 >= 2 * SEG) ? 2 : (F2 >= SEG) ? 1 : 0;
            long r = F2 - (long)which * SEG;
            long n = r >> 12, k = r & 4095;
            const float* vs = (which == 0) ? xv11 : (which == 1) ? xv12 : (which == 2) ? xv21 : xv22;
            src = vs + r;
            bf16* wb = (which < 2) ? xWl : xWr;
            dst = wb + n * KCAT + ((which & 1) ? FF : 0) + k;
        }
    };
    auto aux_step = [&](int ph, int t) {
        if (MODE != 1) return;
        // store prev slice (loaded last phase)
        if (auxDst) {
            bf16x4 o;
            o[0] = (__bf16)auxData.x; o[1] = (__bf16)auxData.y;
            o[2] = (__bf16)auxData.z; o[3] = (__bf16)auxData.w;
            *(bf16x4*)auxDst = o;
            auxDst = nullptr;
        }
        int sid = auxBase + t * 2 + ph;
        if (sid < 40960) {
            const float* src; bf16* dst;
            aux_calc(sid, src, dst);
            auxData = *(const float4*)src;
            auxDst  = dst;
        }
    };

    f32x4 acc[8][4];
    #pragma unroll
    for (int i = 0; i < 8; ++i)
        #pragma unroll
        for (int j = 0; j < 4; ++j)
            acc[i][j] = (f32x4){0.f, 0.f, 0.f, 0.f};

    // prologue: stage all 4 planes of tile 0 into buf0 (order A_k0,B_k0,A_k1,B_k1)
    __builtin_amdgcn_global_load_lds(AS1(gA[0]),      AS3(smem +     0 + ldst), 16, 0, 0);
    __builtin_amdgcn_global_load_lds(AS1(gA[1]),      AS3(smem +  8192 + ldst), 16, 0, 0);
    __builtin_amdgcn_global_load_lds(AS1(gB[0]),      AS3(smem + 32768 + ldst), 16, 0, 0);
    __builtin_amdgcn_global_load_lds(AS1(gB[1]),      AS3(smem + 40960 + ldst), 16, 0, 0);
    __builtin_amdgcn_global_load_lds(AS1(gA[0] + 64), AS3(smem + 16384 + ldst), 16, 0, 0);
    __builtin_amdgcn_global_load_lds(AS1(gA[1] + 64), AS3(smem + 24576 + ldst), 16, 0, 0);
    __builtin_amdgcn_global_load_lds(AS1(gB[0] + 64), AS3(smem + 49152 + ldst), 16, 0, 0);
    __builtin_amdgcn_global_load_lds(AS1(gB[1] + 64), AS3(smem + 57344 + ldst), 16, 0, 0);
    // gate planes A_k0,B_k0 of tile 0 (first 4 loads), then preload ph0 frags
    asm volatile("s_waitcnt vmcnt(4)\n\ts_barrier" ::: "memory");

    bf16x8 afA[4], afB[4], bv0[4], bv1[4];
    #pragma unroll
    for (int f = 0; f < 4; ++f) {
        afA[f] = *(const bf16x8*)(smem +     0 + aoff + f * 1024);   // A_k0 h0
        bv0[f] = *(const bf16x8*)(smem + 32768 + boff + f * 1024);   // B_k0
    }

#define MFMA16(AF, BV, IH)                                                              \
    __builtin_amdgcn_s_setprio(1);                                                      \
    _Pragma("unroll")                                                                   \
    for (int fi = 0; fi < 4; ++fi) {                                                    \
        acc[(IH)*4+fi][0] = __builtin_amdgcn_mfma_f32_16x16x32_bf16(AF[fi], BV[0], acc[(IH)*4+fi][0], 0, 0, 0); \
        acc[(IH)*4+fi][1] = __builtin_amdgcn_mfma_f32_16x16x32_bf16(AF[fi], BV[1], acc[(IH)*4+fi][1], 0, 0, 0); \
        acc[(IH)*4+fi][2] = __builtin_amdgcn_mfma_f32_16x16x32_bf16(AF[fi], BV[2], acc[(IH)*4+fi][2], 0, 0, 0); \
        acc[(IH)*4+fi][3] = __builtin_amdgcn_mfma_f32_16x16x32_bf16(AF[fi], BV[3], acc[(IH)*4+fi][3], 0, 0, 0); \
    }                                                                                   \
    __builtin_amdgcn_s_setprio(0);

    for (int t = 0; t < nt; ++t) {
        const char* pb = smem + (t & 1) * 65536;
        char*       pt = smem + ((t + 1) & 1) * 65536;
        const bool  st = (t + 1 < nt);
        const long  koff = (long)(t + 1) * 128;

        // ---- ph0: MFMA(afA,bv0)->acc[0..3]; read afB <- A_k0 h1; stage A_k0(t+1)
        aux_step(0, t);
        if (st) {
            __builtin_amdgcn_global_load_lds(AS1(gA[0] + koff), AS3(pt +    0 + ldst), 16, 0, 0);
            __builtin_amdgcn_global_load_lds(AS1(gA[1] + koff), AS3(pt + 8192 + ldst), 16, 0, 0);
        }
        asm volatile("s_barrier" ::: "memory");
        #pragma unroll
        for (int f = 0; f < 4; ++f)
            afB[f] = *(const bf16x8*)(pb + 4096 + aoff + f * 1024);
        MFMA16(afA, bv0, 0)

        // ---- ph1: MFMA(afB,bv0)->acc[4..7]; read afA <- A_k1 h0, bv1 <- B_k1; stage B_k0(t+1)
        aux_step(1, t);
        if (st) {
            __builtin_amdgcn_global_load_lds(AS1(gB[0] + koff), AS3(pt + 32768 + ldst), 16, 0, 0);
            __builtin_amdgcn_global_load_lds(AS1(gB[1] + koff), AS3(pt + 40960 + ldst), 16, 0, 0);
            asm volatile("s_waitcnt vmcnt(4)" ::: "memory");
        } else {
            asm volatile("s_waitcnt vmcnt(0)" ::: "memory");
        }
        asm volatile("s_barrier" ::: "memory");
        #pragma unroll
        for (int f = 0; f < 4; ++f) {
            afA[f] = *(const bf16x8*)(pb + 16384 + aoff + f * 1024);   // A_k1 h0
            bv1[f] = *(const bf16x8*)(pb + 49152 + boff + f * 1024);   // B_k1
        }
        MFMA16(afB, bv0, 1)

        // ---- ph2: MFMA(afA,bv1)->acc[0..3]; read afB <- A_k1 h1; stage A_k1(t+1)
        if (st) {
            __builtin_amdgcn_global_load_lds(AS1(gA[0] + koff + 64), AS3(pt + 16384 + ldst), 16, 0, 0);
            __builtin_amdgcn_global_load_lds(AS1(gA[1] + koff + 64), AS3(pt + 24576 + ldst), 16, 0, 0);
        }
        asm volatile("s_barrier" ::: "memory");
        #pragma unroll
        for (int f = 0; f < 4; ++f)
            afB[f] = *(const bf16x8*)(pb + 16384 + 4096 + aoff + f * 1024);
        MFMA16(afA, bv1, 0)

        // ---- ph3: MFMA(afB,bv1)->acc[4..7]; read afA,bv0 <- NEXT tile (from pt); stage B_k1(t+1)
        if (st) {
            __builtin_amdgcn_global_load_lds(AS1(gB[0] + koff + 64), AS3(pt + 49152 + ldst), 16, 0, 0);
            __builtin_amdgcn_global_load_lds(AS1(gB[1] + koff + 64), AS3(pt + 57344 + ldst), 16, 0, 0);
            asm volatile("s_waitcnt vmcnt(4)" ::: "memory");
        }
        asm volatile("s_barrier" ::: "memory");
        if (st) {
            #pragma unroll
            for (int f = 0; f < 4; ++f) {
                afA[f] = *(const bf16x8*)(pt +     0 + aoff + f * 1024);   // A_k0(t+1) h0
                bv0[f] = *(const bf16x8*)(pt + 32768 + boff + f * 1024);   // B_k0(t+1)
            }
        }
        MFMA16(afB, bv1, 1)
    }
#undef MFMA16

    // flush pending aux slice
    if (MODE == 1 && auxDst) {
        bf16x4 o;
        o[0] = (__bf16)auxData.x; o[1] = (__bf16)auxData.y;
        o[2] = (__bf16)auxData.z; o[3] = (__bf16)auxData.w;
        *(bf16x4*)auxDst = o;
    }

    // epilogue: row = row0 + wm*128 + i*16 + (lane>>4)*4 + e ; col = col0 + wn*64 + j*16 + r16
    const int rb = (lane >> 4) * 4;
    #pragma unroll
    for (int i = 0; i < 8; ++i) {
        #pragma unroll
        for (int j = 0; j < 4; ++j) {
            const int cc = col0 + wn * 64 + j * 16 + r16;
            float badd = 0.f;
            if (MODE == 1) badd = bias[cc];
            #pragma unroll
            for (int e = 0; e < 4; ++e) {
                long row = row0 + wm * 128 + i * 16 + rb + e;
                float v = acc[i][j][e];
                if (MODE == 1) {
                    v += badd;
                    v = fmaxf(v, 0.f);
                    v = v * v;
                    ((bf16*)Cout)[row * ldc + cc] = __float2bfloat16(v);
                } else {
                    ((float*)Cout)[row * ldc + cc] = v;
                }
            }
        }
    }
}

// ---------------- glue: per-token gating / tiny einsums ----------------
// In:  Yl[:,0:4096]=x1 raw bf16; Yl[:,4096:8192]=g1 bf16 (aux-written);
//      Yr[:,4096:8192]=x2 raw bf16; Yr[:,0:4096]=g2 bf16 (aux-written)
// Out: Yl = [x1*g1s | y12 | g1s]; Yr = [y21 | x2*g2s | g2s]  (all bf16)
#define GPAD 524   // 8-row pad: h-stride hits 8 distinct banks; 524*4%16==0
__global__ __launch_bounds__(256)
void glue(bf16* __restrict__ Yl, bf16* __restrict__ Yr)
{
    __shared__ __align__(16) float g1t[8 * GPAD];
    __shared__ __align__(16) float g2t[8 * GPAD];
    __shared__ float g1s[EE], g2s[EE];
    __shared__ float t1s[64], t2s[64];
    __shared__ float t1p[4][64], t2p[4][64];
    __shared__ __align__(16) bf16 x1t[FF], x2t[FF];

    const int t   = blockIdx.x;
    const int tid = threadIdx.x;
    bf16* ylp = Yl + (size_t)t * KCAT;
    bf16* yrp = Yr + (size_t)t * KCAT;
    const bf16* g1p = ylp + FF;   // g1 bf16 in y12 slot
    const bf16* g2p = yrp;        // g2 bf16 in y21 slot

    // stage g (bf16 -> f32 LDS, padded) and x
    #pragma unroll
    for (int c = 0; c < 2; ++c) {
        int idx8 = (c * 256 + tid) * 8;
        bf16x8 v1 = *(const bf16x8*)(g1p + idx8);
        bf16x8 v2 = *(const bf16x8*)(g2p + idx8);
        int h = idx8 >> 9, e = idx8 & 511;
        float4 a1 = {(float)v1[0], (float)v1[1], (float)v1[2], (float)v1[3]};
        float4 b1v = {(float)v1[4], (float)v1[5], (float)v1[6], (float)v1[7]};
        float4 a2 = {(float)v2[0], (float)v2[1], (float)v2[2], (float)v2[3]};
        float4 b2v = {(float)v2[4], (float)v2[5], (float)v2[6], (float)v2[7]};
        *(float4*)&g1t[h * GPAD + e]     = a1;
        *(float4*)&g1t[h * GPAD + e + 4] = b1v;
        *(float4*)&g2t[h * GPAD + e]     = a2;
        *(float4*)&g2t[h * GPAD + e + 4] = b2v;
    }
    #pragma unroll
    for (int c = 0; c < 2; ++c) {
        int idx8 = (c * 256 + tid) * 8;
        *(bf16x8*)&x1t[idx8] = *(const bf16x8*)(ylp + idx8);
        *(bf16x8*)&x2t[idx8] = *(const bf16x8*)(yrp + FF + idx8);
    }
    __syncthreads();

    #pragma unroll
    for (int c = 0; c < 2; ++c) {
        int e = c * 256 + tid;
        float s1 = 0.f, s2 = 0.f;
        #pragma unroll
        for (int h = 0; h < 8; ++h) { s1 += g1t[h * GPAD + e]; s2 += g2t[h * GPAD + e]; }
        g1s[e] = s1; g2s[e] = s2;
    }

    {   // t1[h,m] = sum_e x1[e,m]*g1[h,e] ; t2 likewise. 4-way partials.
        int o = tid & 63;
        int h = o & 7, m = o >> 3;
        int p = tid >> 6;
        float s1 = 0.f, s2 = 0.f;
        #pragma unroll 8
        for (int ii = 0; ii < 128; ++ii) {
            int e = p * 128 + ii;
            float xv1 = __bfloat162float(x1t[e * 8 + m]);
            float xv2 = __bfloat162float(x2t[e * 8 + m]);
            s1 += xv1 * g1t[h * GPAD + e];
            s2 += xv2 * g2t[h * GPAD + e];
        }
        t1p[p][o] = s1; t2p[p][o] = s2;
    }
    __syncthreads();
    if (tid < 64)       t1s[tid] = t1p[0][tid] + t1p[1][tid] + t1p[2][tid] + t1p[3][tid];
    else if (tid < 128) { int o = tid - 64; t2s[o] = t2p[0][o] + t2p[1][o] + t2p[2][o] + t2p[3][o]; }
    __syncthreads();

    #pragma unroll
    for (int c = 0; c < 2; ++c) {
        int f0 = (c * 256 + tid) * 8;
        int e  = f0 >> 3;
        float s1 = g1s[e], s2 = g2s[e];
        bf16x8 xa = *(const bf16x8*)&x1t[f0];
        bf16x8 xb = *(const bf16x8*)&x2t[f0];
        bf16x8 o1, o2;
        #pragma unroll
        for (int u = 0; u < 8; ++u) {
            o1[u] = (__bf16)((float)xa[u] * s1);
            o2[u] = (__bf16)((float)xb[u] * s2);
        }
        *(bf16x8*)(ylp + f0)      = o1;
        *(bf16x8*)(yrp + FF + f0) = o2;
    }
    #pragma unroll
    for (int c = 0; c < 2; ++c) {
        int f0 = (c * 256 + tid) * 8;
        int i  = f0 >> 3;
        bf16x8 o12v, o21v;
        #pragma unroll
        for (int m = 0; m < 8; ++m) {
            float s12 = 0.f, s21 = 0.f;
            #pragma unroll
            for (int h = 0; h < 8; ++h) {
                s12 += t2s[(m << 3) | h] * g1t[h * GPAD + i];
                s21 += t1s[(m << 3) | h] * g2t[h * GPAD + i];
            }
            o12v[m] = (__bf16)s12;
            o21v[m] = (__bf16)s21;
        }
        *(bf16x8*)(ylp + FF + f0) = o12v;   // overwrites g1 slice (already staged)
        *(bf16x8*)(yrp + f0)      = o21v;   // overwrites g2 slice
    }
    {
        int e0 = tid * 2;
        ylp[2 * FF + e0]     = __float2bfloat16(g1s[e0]);
        ylp[2 * FF + e0 + 1] = __float2bfloat16(g1s[e0 + 1]);
        yrp[2 * FF + e0]     = __float2bfloat16(g2s[e0]);
        yrp[2 * FF + e0 + 1] = __float2bfloat16(g2s[e0 + 1]);
    }
}

// ---------------- launch ----------------

extern "C" void kernel_launch(void* const* d_in, const int* in_sizes, int n_in,
                              void* d_out, int out_size, void* d_ws, size_t ws_size,
                              hipStream_t stream) {
    const float* x    = (const float*)d_in[0];
    const float* g1   = (const float*)d_in[1];
    const float* g2   = (const float*)d_in[2];
    const float* u1_w = (const float*)d_in[3];
    const float* u1_b = (const float*)d_in[4];
    const float* u2_w = (const float*)d_in[5];
    const float* u2_b = (const float*)d_in[6];
    const float* v11  = (const float*)d_in[7];
    const float* v12  = (const float*)d_in[8];
    const float* v21  = (const float*)d_in[9];
    const float* v22  = (const float*)d_in[10];
    const float* b1   = (const float*)d_in[11];
    const float* b2   = (const float*)d_in[12];
    float* out = (float*)d_out;

    size_t off = 0;
    char* base = (char*)d_ws;
    auto take = [&](size_t bytes) { void* p = base + off; off += (bytes + 255) & ~(size_t)255; return p; };
    bf16* Xb  = (bf16*)take((size_t)TOK * DD * 2);
    bf16* U1b = (bf16*)take((size_t)FF * DD * 2);
    bf16* U2b = (bf16*)take((size_t)FF * DD * 2);
    bf16* Wl  = (bf16*)take((size_t)HALF * KCAT * 2);
    bf16* Wr  = (bf16*)take((size_t)HALF * KCAT * 2);
    bf16* Yl  = (bf16*)take((size_t)TOK * KCAT * 2);
    bf16* Yr  = (bf16*)take((size_t)TOK * KCAT * 2);

    // prep (only what U depends on, plus tiny bmat tails)
    cvt_bf16<<<4096, 256, 0, stream>>>(x,    Xb,  TOK * DD / 4);
    cvt_bf16<<<2048, 256, 0, stream>>>(u1_w, U1b, FF * DD / 4);
    cvt_bf16<<<2048, 256, 0, stream>>>(u2_w, U2b, FF * DD / 4);
    pack_b<<<HALF, 256, 0, stream>>>(b1, b2, Wl, Wr);

    // fused U-GEMMs (+aux: g->bf16 into Yl/Yr slots, v-weights -> Wl/Wr)
    gemmP<1><<<2 * (TOK / 256) * (FF / 256), 512, 0, stream>>>(
        Xb, U1b, u1_b, Yl,
        Xb, U2b, u2_b, Yr + FF,
        TOK / 256, FF / 256, DD, KCAT,
        g1, g2, v11, v12, v21, v22, Yl, Yr, Wl, Wr);

    // gating / tiny einsums (g read from Yl/Yr aux slots)
    glue<<<TOK, 256, 0, stream>>>(Yl, Yr);

    // fused V-GEMMs: out[:,0:1024] = Yl @ Wl^T ; out[:,1024:2048] = Yr @ Wr^T  (fp32)
    gemmP<0><<<2 * (TOK / 256) * (HALF / 256), 512, 0, stream>>>(
        Yl, Wl, nullptr, out,
        Yr, Wr, nullptr, out + HALF,
        TOK / 256, HALF / 256, KCAT, DD,
        nullptr, nullptr, nullptr, nullptr, nullptr, nullptr,
        nullptr, nullptr, nullptr, nullptr);
}

// Round 12
// 685.040 us; speedup vs baseline: 1.1959x; 1.1959x over previous
//
#include <hip/hip_runtime.h>
#include <hip/hip_bf16.h>

// MonetMoVDE: B=4 T=2048 D=2048 H=8 E=512 M=8, F=4096, HALF=1024
#define TOK   8192   // B*T
#define DD    2048
#define FF    4096
#define EE    512
#define HALF  1024
#define KCAT  8704   // F + F + E  (concat K for V-GEMMs, 8704 = 136*64)

typedef __bf16 bf16x8 __attribute__((ext_vector_type(8)));
typedef __bf16 bf16x4 __attribute__((ext_vector_type(4)));
typedef float  f32x4  __attribute__((ext_vector_type(4)));
using bf16 = __hip_bfloat16;

#define AS1(p) ((const __attribute__((address_space(1))) void*)(p))
#define AS3(p) ((__attribute__((address_space(3))) void*)(p))

// ---------------- fused prep: x/u1/u2 cvt + v-weight pack + bmat tails ----------------
// Virtual index space (float4 slots unless noted):
//  [0, R0): x cvt            R0 = TOK*DD/4      = 4194304
//  [R0,R1): u1 cvt           +FF*DD/4           = 6291456
//  [R1,R2): u2 cvt           +FF*DD/4           = 8388608
//  [R2,R3): Wl pack (v11|v12) +HALF*FF/2        = 10485760
//  [R3,R4): Wr pack (v21|v22) +HALF*FF/2        = 12582912
//  [R4,R5): bmat tails (scalar) +2*HALF*EE      = 13631488
#define PR0 4194304u
#define PR1 6291456u
#define PR2 8388608u
#define PR3 10485760u
#define PR4 12582912u
#define PR5 13631488u
__global__ __launch_bounds__(256)
void prep_all(const float* __restrict__ x, const float* __restrict__ u1_w,
              const float* __restrict__ u2_w,
              const float* __restrict__ v11, const float* __restrict__ v12,
              const float* __restrict__ v21, const float* __restrict__ v22,
              const float* __restrict__ b1, const float* __restrict__ b2,
              bf16* __restrict__ Xb, bf16* __restrict__ U1b, bf16* __restrict__ U2b,
              bf16* __restrict__ Wl, bf16* __restrict__ Wr)
{
    const unsigned stride = gridDim.x * blockDim.x;
    for (unsigned i = blockIdx.x * blockDim.x + threadIdx.x; i < PR5; i += stride) {
        if (i < PR2) {
            const float* src; bf16* dst; unsigned s;
            if (i < PR0)      { s = i;        src = x;    dst = Xb;  }
            else if (i < PR1) { s = i - PR0;  src = u1_w; dst = U1b; }
            else              { s = i - PR1;  src = u2_w; dst = U2b; }
            float4 v = ((const float4*)src)[s];
            bf16x4 o;
            o[0] = (__bf16)v.x; o[1] = (__bf16)v.y; o[2] = (__bf16)v.z; o[3] = (__bf16)v.w;
            ((bf16x4*)dst)[s] = o;
        } else if (i < PR4) {
            const bool left = (i < PR3);
            unsigned s = i - (left ? PR2 : PR3);
            unsigned n = s >> 11, j = s & 2047;
            const float* vs = left ? (j < 1024 ? v11 : v12) : (j < 1024 ? v21 : v22);
            unsigned jj = (j < 1024) ? j : (j - 1024);
            float4 v = *(const float4*)(vs + (size_t)n * FF + jj * 4);
            bf16x4 o;
            o[0] = (__bf16)v.x; o[1] = (__bf16)v.y; o[2] = (__bf16)v.z; o[3] = (__bf16)v.w;
            bf16* wb = left ? Wl : Wr;
            *(bf16x4*)(wb + (size_t)n * KCAT + ((j < 1024) ? 0 : FF) + jj * 4) = o;
        } else {
            unsigned s = i - PR4;
            const bool left = (s < (unsigned)(HALF * EE));
            unsigned r = left ? s : s - HALF * EE;
            unsigned n = r >> 9, e = r & 511;
            const float* bm = left ? b1 : b2;
            bf16* wb = left ? Wl : Wr;
            wb[(size_t)n * KCAT + 2 * FF + e] = __float2bfloat16(bm[(size_t)e * HALF + n]);
        }
    }
}

// ---------------- GEMM: C[m,n] = sum_k A[m,k] * Bw[n,k] ----------------
// r6-exact structure (best verified: 46% MfmaUtil, 0 bank conflicts, 265-270us).
// 256x256 tile, BK=64, 8 waves (2Mx4N), 16x16x32 MFMA, per-wave C 128x64.
// LDS buffer (64KB) = 4 planes of 16KB: A_k0 @0, A_k1 @16K, B_k0 @32K, B_k1 @48K.
// Plane = 256 rows x 64B, swizzle byte ^= (((row>>1)&3)<<4) - proven zero-conflict.
// REGISTER-PIPELINED phases: each phase {stage 2 chunk-gloads; [vmcnt]; barrier;
// ds_read NEXT phase's frags; MFMA on frags read LAST phase}. One barrier/phase;
// counted vmcnt(4) (stores not mixed into the ledger - r11 lesson), 0 only at tail.
// Fused dual-GEMM; MODE 0: fp32 store, MODE 1: relu(z+bias)^2 -> bf16 store.
template<int MODE>
__global__ __launch_bounds__(512, 2)
void gemmP(const bf16* __restrict__ A0, const bf16* __restrict__ B0,
           const float* __restrict__ bias0, void* __restrict__ C0,
           const bf16* __restrict__ A1, const bf16* __restrict__ B1,
           const float* __restrict__ bias1, void* __restrict__ C1,
           int nbm, int nbn, int K, int ldc)
{
    __shared__ __align__(16) char smem[131072];   // 2 x 64KB
    const int tid  = threadIdx.x;
    const int lane = tid & 63;
    const int wid  = tid >> 6;
    const int wm = wid >> 2, wn = wid & 3;
    const int r16 = lane & 15, kb = lane >> 4;

    int bid = blockIdx.x;
    {   // bijective XCD swizzle (m204)
        int nwg = gridDim.x;
        int q = nwg >> 3, r = nwg & 7;
        int xcd = bid & 7, idx = bid >> 3;
        bid = (xcd < r ? xcd * (q + 1) : r * (q + 1) + (xcd - r) * q) + idx;
    }
    const int npg = nbm * nbn;
    const int g   = bid / npg;
    const int lb  = bid - g * npg;
    const int bm = lb / nbn, bn = lb - bm * nbn;

    const bf16*  A    = g ? A1 : A0;
    const bf16*  Bw   = g ? B1 : B0;
    const float* bias = g ? bias1 : bias0;
    char* Cout = (char*)(g ? C1 : C0);

    const long row0 = (long)bm * 256;
    const int  col0 = bn * 256;
    const int  nt   = K >> 6;

    // staging sources (pre-swizzled; involution) + linear LDS dest offset
    const char* gA[2]; const char* gB[2];
    #pragma unroll
    for (int l = 0; l < 2; ++l) {
        const uint32_t S = (uint32_t)(l * 512 + tid) * 16;   // byte slot in 16KB plane
        const int r  = (int)(S >> 6);                        // plane row 0..255
        const int cb = (int)((S & 63) ^ ((uint32_t)((r >> 1) & 3) << 4));
        gA[l] = (const char*)A  + (row0 + r) * (long)K * 2 + cb;
        gB[l] = (const char*)Bw + (long)(col0 + r) * K * 2 + cb;
    }
    const uint32_t ldst = (uint32_t)(tid & ~63) * 16;        // + l*8192 + plane base

    // per-lane read base offsets within a plane (swizzled; proven zero-conflict)
    const uint32_t swz  = ((uint32_t)(r16 >> 1) & 3u) << 4;
    const uint32_t aoff = (uint32_t)((wm * 128 + r16) * 64 + kb * 16) ^ swz;  // +4096 for row-half1, +fi*1024
    const uint32_t boff = (uint32_t)((wn * 64  + r16) * 64 + kb * 16) ^ swz;  // +fj*1024

    f32x4 acc[8][4];
    #pragma unroll
    for (int i = 0; i < 8; ++i)
        #pragma unroll
        for (int j = 0; j < 4; ++j)
            acc[i][j] = (f32x4){0.f, 0.f, 0.f, 0.f};

    // prologue: stage all 4 planes of tile 0 into buf0 (order A_k0,B_k0,A_k1,B_k1)
    __builtin_amdgcn_global_load_lds(AS1(gA[0]),      AS3(smem +     0 + ldst), 16, 0, 0);
    __builtin_amdgcn_global_load_lds(AS1(gA[1]),      AS3(smem +  8192 + ldst), 16, 0, 0);
    __builtin_amdgcn_global_load_lds(AS1(gB[0]),      AS3(smem + 32768 + ldst), 16, 0, 0);
    __builtin_amdgcn_global_load_lds(AS1(gB[1]),      AS3(smem + 40960 + ldst), 16, 0, 0);
    __builtin_amdgcn_global_load_lds(AS1(gA[0] + 64), AS3(smem + 16384 + ldst), 16, 0, 0);
    __builtin_amdgcn_global_load_lds(AS1(gA[1] + 64), AS3(smem + 24576 + ldst), 16, 0, 0);
    __builtin_amdgcn_global_load_lds(AS1(gB[0] + 64), AS3(smem + 49152 + ldst), 16, 0, 0);
    __builtin_amdgcn_global_load_lds(AS1(gB[1] + 64), AS3(smem + 57344 + ldst), 16, 0, 0);
    // gate planes A_k0,B_k0 of tile 0 (first 4 loads), then preload ph0 frags
    asm volatile("s_waitcnt vmcnt(4)\n\ts_barrier" ::: "memory");

    bf16x8 afA[4], afB[4], bv0[4], bv1[4];
    #pragma unroll
    for (int f = 0; f < 4; ++f) {
        afA[f] = *(const bf16x8*)(smem +     0 + aoff + f * 1024);   // A_k0 h0
        bv0[f] = *(const bf16x8*)(smem + 32768 + boff + f * 1024);   // B_k0
    }

#define MFMA16(AF, BV, IH)                                                              \
    __builtin_amdgcn_s_setprio(1);                                                      \
    _Pragma("unroll")                                                                   \
    for (int fi = 0; fi < 4; ++fi) {                                                    \
        acc[(IH)*4+fi][0] = __builtin_amdgcn_mfma_f32_16x16x32_bf16(AF[fi], BV[0], acc[(IH)*4+fi][0], 0, 0, 0); \
        acc[(IH)*4+fi][1] = __builtin_amdgcn_mfma_f32_16x16x32_bf16(AF[fi], BV[1], acc[(IH)*4+fi][1], 0, 0, 0); \
        acc[(IH)*4+fi][2] = __builtin_amdgcn_mfma_f32_16x16x32_bf16(AF[fi], BV[2], acc[(IH)*4+fi][2], 0, 0, 0); \
        acc[(IH)*4+fi][3] = __builtin_amdgcn_mfma_f32_16x16x32_bf16(AF[fi], BV[3], acc[(IH)*4+fi][3], 0, 0, 0); \
    }                                                                                   \
    __builtin_amdgcn_s_setprio(0);

    for (int t = 0; t < nt; ++t) {
        const char* pb = smem + (t & 1) * 65536;
        char*       pt = smem + ((t + 1) & 1) * 65536;
        const bool  st = (t + 1 < nt);
        const long  koff = (long)(t + 1) * 128;

        // ---- ph0: MFMA(afA,bv0)->acc[0..3]; read afB <- A_k0 h1; stage A_k0(t+1)
        if (st) {
            __builtin_amdgcn_global_load_lds(AS1(gA[0] + koff), AS3(pt +    0 + ldst), 16, 0, 0);
            __builtin_amdgcn_global_load_lds(AS1(gA[1] + koff), AS3(pt + 8192 + ldst), 16, 0, 0);
        }
        asm volatile("s_barrier" ::: "memory");
        #pragma unroll
        for (int f = 0; f < 4; ++f)
            afB[f] = *(const bf16x8*)(pb + 4096 + aoff + f * 1024);
        MFMA16(afA, bv0, 0)

        // ---- ph1: MFMA(afB,bv0)->acc[4..7]; read afA <- A_k1 h0, bv1 <- B_k1; stage B_k0(t+1)
        if (st) {
            __builtin_amdgcn_global_load_lds(AS1(gB[0] + koff), AS3(pt + 32768 + ldst), 16, 0, 0);
            __builtin_amdgcn_global_load_lds(AS1(gB[1] + koff), AS3(pt + 40960 + ldst), 16, 0, 0);
            asm volatile("s_waitcnt vmcnt(4)" ::: "memory");
        } else {
            asm volatile("s_waitcnt vmcnt(0)" ::: "memory");
        }
        asm volatile("s_barrier" ::: "memory");
        #pragma unroll
        for (int f = 0; f < 4; ++f) {
            afA[f] = *(const bf16x8*)(pb + 16384 + aoff + f * 1024);   // A_k1 h0
            bv1[f] = *(const bf16x8*)(pb + 49152 + boff + f * 1024);   // B_k1
        }
        MFMA16(afB, bv0, 1)

        // ---- ph2: MFMA(afA,bv1)->acc[0..3]; read afB <- A_k1 h1; stage A_k1(t+1)
        if (st) {
            __builtin_amdgcn_global_load_lds(AS1(gA[0] + koff + 64), AS3(pt + 16384 + ldst), 16, 0, 0);
            __builtin_amdgcn_global_load_lds(AS1(gA[1] + koff + 64), AS3(pt + 24576 + ldst), 16, 0, 0);
        }
        asm volatile("s_barrier" ::: "memory");
        #pragma unroll
        for (int f = 0; f < 4; ++f)
            afB[f] = *(const bf16x8*)(pb + 16384 + 4096 + aoff + f * 1024);
        MFMA16(afA, bv1, 0)

        // ---- ph3: MFMA(afB,bv1)->acc[4..7]; read afA,bv0 <- NEXT tile (from pt); stage B_k1(t+1)
        if (st) {
            __builtin_amdgcn_global_load_lds(AS1(gB[0] + koff + 64), AS3(pt + 49152 + ldst), 16, 0, 0);
            __builtin_amdgcn_global_load_lds(AS1(gB[1] + koff + 64), AS3(pt + 57344 + ldst), 16, 0, 0);
            asm volatile("s_waitcnt vmcnt(4)" ::: "memory");
        }
        asm volatile("s_barrier" ::: "memory");
        if (st) {
            #pragma unroll
            for (int f = 0; f < 4; ++f) {
                afA[f] = *(const bf16x8*)(pt +     0 + aoff + f * 1024);   // A_k0(t+1) h0
                bv0[f] = *(const bf16x8*)(pt + 32768 + boff + f * 1024);   // B_k0(t+1)
            }
        }
        MFMA16(afB, bv1, 1)
    }
#undef MFMA16

    // epilogue: row = row0 + wm*128 + i*16 + (lane>>4)*4 + e ; col = col0 + wn*64 + j*16 + r16
    const int rb = (lane >> 4) * 4;
    #pragma unroll
    for (int i = 0; i < 8; ++i) {
        #pragma unroll
        for (int j = 0; j < 4; ++j) {
            const int cc = col0 + wn * 64 + j * 16 + r16;
            float badd = 0.f;
            if (MODE == 1) badd = bias[cc];
            #pragma unroll
            for (int e = 0; e < 4; ++e) {
                long row = row0 + wm * 128 + i * 16 + rb + e;
                float v = acc[i][j][e];
                if (MODE == 1) {
                    v += badd;
                    v = fmaxf(v, 0.f);
                    v = v * v;
                    ((bf16*)Cout)[row * ldc + cc] = __float2bfloat16(v);
                } else {
                    ((float*)Cout)[row * ldc + cc] = v;
                }
            }
        }
    }
}

// ---------------- glue: per-token gating / tiny einsums ----------------
// In:  g1,g2 [TOK][8][512] f32; Yl[:,0:4096]=x1 raw bf16; Yr[:,4096:8192]=x2 raw bf16
// Out: Yl = [x1*g1s | y12 | g1s]; Yr = [y21 | x2*g2s | g2s]  (all bf16)
#define GPAD 524   // 8-row pad: h-stride hits 8 distinct banks; 524*4%16==0
__global__ __launch_bounds__(256)
void glue(const float* __restrict__ g1, const float* __restrict__ g2,
          bf16* __restrict__ Yl, bf16* __restrict__ Yr)
{
    __shared__ __align__(16) float g1t[8 * GPAD];
    __shared__ __align__(16) float g2t[8 * GPAD];
    __shared__ float g1s[EE], g2s[EE];
    __shared__ float t1s[64], t2s[64];
    __shared__ float t1p[4][64], t2p[4][64];
    __shared__ __align__(16) bf16 x1t[FF], x2t[FF];

    const int t   = blockIdx.x;
    const int tid = threadIdx.x;
    const float* g1p = g1 + (size_t)t * FF;
    const float* g2p = g2 + (size_t)t * FF;
    bf16* ylp = Yl + (size_t)t * KCAT;
    bf16* yrp = Yr + (size_t)t * KCAT;

    #pragma unroll
    for (int c = 0; c < 4; ++c) {
        int idx4 = (c * 256 + tid) * 4;
        float4 v1 = *(const float4*)(g1p + idx4);
        float4 v2 = *(const float4*)(g2p + idx4);
        int h = idx4 >> 9, e = idx4 & 511;
        *(float4*)&g1t[h * GPAD + e] = v1;
        *(float4*)&g2t[h * GPAD + e] = v2;
    }
    #pragma unroll
    for (int c = 0; c < 2; ++c) {
        int idx8 = (c * 256 + tid) * 8;
        *(bf16x8*)&x1t[idx8] = *(const bf16x8*)(ylp + idx8);
        *(bf16x8*)&x2t[idx8] = *(const bf16x8*)(yrp + FF + idx8);
    }
    __syncthreads();

    #pragma unroll
    for (int c = 0; c < 2; ++c) {
        int e = c * 256 + tid;
        float s1 = 0.f, s2 = 0.f;
        #pragma unroll
        for (int h = 0; h < 8; ++h) { s1 += g1t[h * GPAD + e]; s2 += g2t[h * GPAD + e]; }
        g1s[e] = s1; g2s[e] = s2;
    }

    {   // t1[h,m] = sum_e x1[e,m]*g1[h,e] ; t2 likewise. 4-way partials.
        int o = tid & 63;
        int h = o & 7, m = o >> 3;
        int p = tid >> 6;
        float s1 = 0.f, s2 = 0.f;
        #pragma unroll 8
        for (int ii = 0; ii < 128; ++ii) {
            int e = p * 128 + ii;
            float xv1 = __bfloat162float(x1t[e * 8 + m]);
            float xv2 = __bfloat162float(x2t[e * 8 + m]);
            s1 += xv1 * g1t[h * GPAD + e];
            s2 += xv2 * g2t[h * GPAD + e];
        }
        t1p[p][o] = s1; t2p[p][o] = s2;
    }
    __syncthreads();
    if (tid < 64)       t1s[tid] = t1p[0][tid] + t1p[1][tid] + t1p[2][tid] + t1p[3][tid];
    else if (tid < 128) { int o = tid - 64; t2s[o] = t2p[0][o] + t2p[1][o] + t2p[2][o] + t2p[3][o]; }
    __syncthreads();

    #pragma unroll
    for (int c = 0; c < 2; ++c) {
        int f0 = (c * 256 + tid) * 8;
        int e  = f0 >> 3;
        float s1 = g1s[e], s2 = g2s[e];
        bf16x8 xa = *(const bf16x8*)&x1t[f0];
        bf16x8 xb = *(const bf16x8*)&x2t[f0];
        bf16x8 o1, o2;
        #pragma unroll
        for (int u = 0; u < 8; ++u) {
            o1[u] = (__bf16)((float)xa[u] * s1);
            o2[u] = (__bf16)((float)xb[u] * s2);
        }
        *(bf16x8*)(ylp + f0)      = o1;
        *(bf16x8*)(yrp + FF + f0) = o2;
    }
    #pragma unroll
    for (int c = 0; c < 2; ++c) {
        int f0 = (c * 256 + tid) * 8;
        int i  = f0 >> 3;
        bf16x8 o12v, o21v;
        #pragma unroll
        for (int m = 0; m < 8; ++m) {
            float s12 = 0.f, s21 = 0.f;
            #pragma unroll
            for (int h = 0; h < 8; ++h) {
                s12 += t2s[(m << 3) | h] * g1t[h * GPAD + i];
                s21 += t1s[(m << 3) | h] * g2t[h * GPAD + i];
            }
            o12v[m] = (__bf16)s12;
            o21v[m] = (__bf16)s21;
        }
        *(bf16x8*)(ylp + FF + f0) = o12v;
        *(bf16x8*)(yrp + f0)      = o21v;
    }
    {
        int e0 = tid * 2;
        ylp[2 * FF + e0]     = __float2bfloat16(g1s[e0]);
        ylp[2 * FF + e0 + 1] = __float2bfloat16(g1s[e0 + 1]);
        yrp[2 * FF + e0]     = __float2bfloat16(g2s[e0]);
        yrp[2 * FF + e0 + 1] = __float2bfloat16(g2s[e0 + 1]);
    }
}

// ---------------- launch ----------------

extern "C" void kernel_launch(void* const* d_in, const int* in_sizes, int n_in,
                              void* d_out, int out_size, void* d_ws, size_t ws_size,
                              hipStream_t stream) {
    const float* x    = (const float*)d_in[0];
    const float* g1   = (const float*)d_in[1];
    const float* g2   = (const float*)d_in[2];
    const float* u1_w = (const float*)d_in[3];
    const float* u1_b = (const float*)d_in[4];
    const float* u2_w = (const float*)d_in[5];
    const float* u2_b = (const float*)d_in[6];
    const float* v11  = (const float*)d_in[7];
    const float* v12  = (const float*)d_in[8];
    const float* v21  = (const float*)d_in[9];
    const float* v22  = (const float*)d_in[10];
    const float* b1   = (const float*)d_in[11];
    const float* b2   = (const float*)d_in[12];
    float* out = (float*)d_out;

    size_t off = 0;
    char* base = (char*)d_ws;
    auto take = [&](size_t bytes) { void* p = base + off; off += (bytes + 255) & ~(size_t)255; return p; };
    bf16* Xb  = (bf16*)take((size_t)TOK * DD * 2);
    bf16* U1b = (bf16*)take((size_t)FF * DD * 2);
    bf16* U2b = (bf16*)take((size_t)FF * DD * 2);
    bf16* Wl  = (bf16*)take((size_t)HALF * KCAT * 2);
    bf16* Wr  = (bf16*)take((size_t)HALF * KCAT * 2);
    bf16* Yl  = (bf16*)take((size_t)TOK * KCAT * 2);
    bf16* Yr  = (bf16*)take((size_t)TOK * KCAT * 2);

    // fused prep: all cvt + weight packing in one dispatch
    prep_all<<<2048, 256, 0, stream>>>(x, u1_w, u2_w, v11, v12, v21, v22, b1, b2,
                                       Xb, U1b, U2b, Wl, Wr);

    // fused U-GEMMs: x1raw -> Yl[:,0:4096], x2raw -> Yr[:,4096:8192]  (relu^2, bf16)
    gemmP<1><<<2 * (TOK / 256) * (FF / 256), 512, 0, stream>>>(
        Xb, U1b, u1_b, Yl,
        Xb, U2b, u2_b, Yr + FF,
        TOK / 256, FF / 256, DD, KCAT);

    // gating / tiny einsums
    glue<<<TOK, 256, 0, stream>>>(g1, g2, Yl, Yr);

    // fused V-GEMMs: out[:,0:1024] = Yl @ Wl^T ; out[:,1024:2048] = Yr @ Wr^T  (fp32)
    gemmP<0><<<2 * (TOK / 256) * (HALF / 256), 512, 0, stream>>>(
        Yl, Wl, nullptr, out,
        Yr, Wr, nullptr, out + HALF,
        TOK / 256, HALF / 256, KCAT, DD);
}

// Round 13
// 684.125 us; speedup vs baseline: 1.1975x; 1.0013x over previous
//
#include <hip/hip_runtime.h>
#include <hip/hip_bf16.h>

// MonetMoVDE: B=4 T=2048 D=2048 H=8 E=512 M=8, F=4096, HALF=1024
#define TOK   8192   // B*T
#define DD    2048
#define FF    4096
#define EE    512
#define HALF  1024
#define KCAT  8704   // F + F + E  (concat K for V-GEMMs, 8704 = 136*64)

typedef __bf16 bf16x8 __attribute__((ext_vector_type(8)));
typedef __bf16 bf16x4 __attribute__((ext_vector_type(4)));
typedef float  f32x4  __attribute__((ext_vector_type(4)));
using bf16 = __hip_bfloat16;

#define AS1(p) ((const __attribute__((address_space(1))) void*)(p))
#define AS3(p) ((__attribute__((address_space(3))) void*)(p))

// ---------------- prep: x/u1/u2 f32->bf16 cvt only ----------------
//  [0, R0): x cvt            R0 = TOK*DD/4      = 4194304
//  [R0,R1): u1 cvt           +FF*DD/4           = 6291456
//  [R1,R2): u2 cvt           +FF*DD/4           = 8388608
#define PR0 4194304u
#define PR1 6291456u
#define PR2 8388608u
__global__ __launch_bounds__(256)
void prep_cvt(const float* __restrict__ x, const float* __restrict__ u1_w,
              const float* __restrict__ u2_w,
              bf16* __restrict__ Xb, bf16* __restrict__ U1b, bf16* __restrict__ U2b)
{
    const unsigned stride = gridDim.x * blockDim.x;
    for (unsigned i = blockIdx.x * blockDim.x + threadIdx.x; i < PR2; i += stride) {
        const float* src; bf16* dst; unsigned s;
        if (i < PR0)      { s = i;        src = x;    dst = Xb;  }
        else if (i < PR1) { s = i - PR0;  src = u1_w; dst = U1b; }
        else              { s = i - PR1;  src = u2_w; dst = U2b; }
        float4 v = ((const float4*)src)[s];
        bf16x4 o;
        o[0] = (__bf16)v.x; o[1] = (__bf16)v.y; o[2] = (__bf16)v.z; o[3] = (__bf16)v.w;
        ((bf16x4*)dst)[s] = o;
    }
}

// ---------------- GEMM: C[m,n] = sum_k A[m,k] * Bw[n,k] ----------------
// r6-exact structure (best verified: 46% MfmaUtil, 0 bank conflicts, 265-276us).
// 256x256 tile, BK=64, 8 waves (2Mx4N), 16x16x32 MFMA, per-wave C 128x64.
// LDS buffer (64KB) = 4 planes of 16KB: A_k0 @0, A_k1 @16K, B_k0 @32K, B_k1 @48K.
// Plane = 256 rows x 64B, swizzle byte ^= (((row>>1)&3)<<4) - proven zero-conflict.
// REGISTER-PIPELINED phases: each phase {stage 2 chunk-gloads; [vmcnt]; barrier;
// ds_read NEXT phase's frags; MFMA on frags read LAST phase}. One barrier/phase;
// counted vmcnt(4) (stores excluded from ledger - r11 lesson), 0 only at tail.
// MODE 1 additionally carries 256 PIGGYBACK PACK BLOCKS (raw blockIdx >= 2*npg,
// LDS-free, co-resident with GEMM blocks): v11|v12->Wl, v21|v22->Wr, bmat tails.
// Separate waves -> no vmcnt-ledger interaction; retire inside U's window;
// consumer (V-GEMM) is 2 dispatches later.
// Fused dual-GEMM; MODE 0: fp32 store, MODE 1: relu(z+bias)^2 -> bf16 store.
template<int MODE>
__global__ __launch_bounds__(512, 2)
void gemmP(const bf16* __restrict__ A0, const bf16* __restrict__ B0,
           const float* __restrict__ bias0, void* __restrict__ C0,
           const bf16* __restrict__ A1, const bf16* __restrict__ B1,
           const float* __restrict__ bias1, void* __restrict__ C1,
           int nbm, int nbn, int K, int ldc,
           const float* __restrict__ xv11, const float* __restrict__ xv12,
           const float* __restrict__ xv21, const float* __restrict__ xv22,
           const float* __restrict__ xb1, const float* __restrict__ xb2,
           bf16* __restrict__ xWl, bf16* __restrict__ xWr)
{
    __shared__ __align__(16) char smem[131072];   // 2 x 64KB
    const int tid  = threadIdx.x;
    const int npg  = nbm * nbn;

    if (MODE == 1 && blockIdx.x >= (unsigned)(2 * npg)) {
        // ---- piggyback pack block (no LDS, no barriers) ----
        const unsigned lane_g = (blockIdx.x - 2 * npg) * 512u + tid;   // [0, 131072)
        #pragma unroll 4
        for (int k = 0; k < 32; ++k) {                                  // 4,194,304 float4 slots
            unsigned w = lane_g + (unsigned)k * 131072u;
            const bool left = w < 2097152u;
            unsigned s = left ? w : w - 2097152u;
            unsigned n = s >> 11, j = s & 2047u;
            const float* vs = left ? (j < 1024u ? xv11 : xv12) : (j < 1024u ? xv21 : xv22);
            unsigned jj = (j < 1024u) ? j : (j - 1024u);
            float4 v = *(const float4*)(vs + (size_t)n * FF + jj * 4);
            bf16x4 o;
            o[0] = (__bf16)v.x; o[1] = (__bf16)v.y; o[2] = (__bf16)v.z; o[3] = (__bf16)v.w;
            bf16* wb = left ? xWl : xWr;
            *(bf16x4*)(wb + (size_t)n * KCAT + ((j < 1024u) ? 0 : FF) + jj * 4) = o;
        }
        #pragma unroll 2
        for (int k = 0; k < 8; ++k) {                                   // 1,048,576 bmat scalars
            unsigned w = lane_g + (unsigned)k * 131072u;
            const bool left = w < 524288u;
            unsigned r = left ? w : w - 524288u;
            unsigned n = r >> 9, e = r & 511u;
            const float* bm = left ? xb1 : xb2;
            bf16* wb = left ? xWl : xWr;
            wb[(size_t)n * KCAT + 2 * FF + e] = __float2bfloat16(bm[(size_t)e * HALF + n]);
        }
        return;
    }

    const int lane = tid & 63;
    const int wid  = tid >> 6;
    const int wm = wid >> 2, wn = wid & 3;
    const int r16 = lane & 15, kb = lane >> 4;

    int bid = blockIdx.x;
    {   // bijective XCD swizzle (m204) over the GEMM blocks only
        int nwg = 2 * npg;
        int q = nwg >> 3, r = nwg & 7;
        int xcd = bid & 7, idx = bid >> 3;
        bid = (xcd < r ? xcd * (q + 1) : r * (q + 1) + (xcd - r) * q) + idx;
    }
    const int g   = bid / npg;
    const int lb  = bid - g * npg;
    const int bm = lb / nbn, bn = lb - bm * nbn;

    const bf16*  A    = g ? A1 : A0;
    const bf16*  Bw   = g ? B1 : B0;
    const float* bias = g ? bias1 : bias0;
    char* Cout = (char*)(g ? C1 : C0);

    const long row0 = (long)bm * 256;
    const int  col0 = bn * 256;
    const int  nt   = K >> 6;

    // staging sources (pre-swizzled; involution) + linear LDS dest offset
    const char* gA[2]; const char* gB[2];
    #pragma unroll
    for (int l = 0; l < 2; ++l) {
        const uint32_t S = (uint32_t)(l * 512 + tid) * 16;   // byte slot in 16KB plane
        const int r  = (int)(S >> 6);                        // plane row 0..255
        const int cb = (int)((S & 63) ^ ((uint32_t)((r >> 1) & 3) << 4));
        gA[l] = (const char*)A  + (row0 + r) * (long)K * 2 + cb;
        gB[l] = (const char*)Bw + (long)(col0 + r) * K * 2 + cb;
    }
    const uint32_t ldst = (uint32_t)(tid & ~63) * 16;        // + l*8192 + plane base

    // per-lane read base offsets within a plane (swizzled; proven zero-conflict)
    const uint32_t swz  = ((uint32_t)(r16 >> 1) & 3u) << 4;
    const uint32_t aoff = (uint32_t)((wm * 128 + r16) * 64 + kb * 16) ^ swz;  // +4096 for row-half1, +fi*1024
    const uint32_t boff = (uint32_t)((wn * 64  + r16) * 64 + kb * 16) ^ swz;  // +fj*1024

    f32x4 acc[8][4];
    #pragma unroll
    for (int i = 0; i < 8; ++i)
        #pragma unroll
        for (int j = 0; j < 4; ++j)
            acc[i][j] = (f32x4){0.f, 0.f, 0.f, 0.f};

    // prologue: stage all 4 planes of tile 0 into buf0 (order A_k0,B_k0,A_k1,B_k1)
    __builtin_amdgcn_global_load_lds(AS1(gA[0]),      AS3(smem +     0 + ldst), 16, 0, 0);
    __builtin_amdgcn_global_load_lds(AS1(gA[1]),      AS3(smem +  8192 + ldst), 16, 0, 0);
    __builtin_amdgcn_global_load_lds(AS1(gB[0]),      AS3(smem + 32768 + ldst), 16, 0, 0);
    __builtin_amdgcn_global_load_lds(AS1(gB[1]),      AS3(smem + 40960 + ldst), 16, 0, 0);
    __builtin_amdgcn_global_load_lds(AS1(gA[0] + 64), AS3(smem + 16384 + ldst), 16, 0, 0);
    __builtin_amdgcn_global_load_lds(AS1(gA[1] + 64), AS3(smem + 24576 + ldst), 16, 0, 0);
    __builtin_amdgcn_global_load_lds(AS1(gB[0] + 64), AS3(smem + 49152 + ldst), 16, 0, 0);
    __builtin_amdgcn_global_load_lds(AS1(gB[1] + 64), AS3(smem + 57344 + ldst), 16, 0, 0);
    // gate planes A_k0,B_k0 of tile 0 (first 4 loads), then preload ph0 frags
    asm volatile("s_waitcnt vmcnt(4)\n\ts_barrier" ::: "memory");

    bf16x8 afA[4], afB[4], bv0[4], bv1[4];
    #pragma unroll
    for (int f = 0; f < 4; ++f) {
        afA[f] = *(const bf16x8*)(smem +     0 + aoff + f * 1024);   // A_k0 h0
        bv0[f] = *(const bf16x8*)(smem + 32768 + boff + f * 1024);   // B_k0
    }

#define MFMA16(AF, BV, IH)                                                              \
    __builtin_amdgcn_s_setprio(1);                                                      \
    _Pragma("unroll")                                                                   \
    for (int fi = 0; fi < 4; ++fi) {                                                    \
        acc[(IH)*4+fi][0] = __builtin_amdgcn_mfma_f32_16x16x32_bf16(AF[fi], BV[0], acc[(IH)*4+fi][0], 0, 0, 0); \
        acc[(IH)*4+fi][1] = __builtin_amdgcn_mfma_f32_16x16x32_bf16(AF[fi], BV[1], acc[(IH)*4+fi][1], 0, 0, 0); \
        acc[(IH)*4+fi][2] = __builtin_amdgcn_mfma_f32_16x16x32_bf16(AF[fi], BV[2], acc[(IH)*4+fi][2], 0, 0, 0); \
        acc[(IH)*4+fi][3] = __builtin_amdgcn_mfma_f32_16x16x32_bf16(AF[fi], BV[3], acc[(IH)*4+fi][3], 0, 0, 0); \
    }                                                                                   \
    __builtin_amdgcn_s_setprio(0);

    for (int t = 0; t < nt; ++t) {
        const char* pb = smem + (t & 1) * 65536;
        char*       pt = smem + ((t + 1) & 1) * 65536;
        const bool  st = (t + 1 < nt);
        const long  koff = (long)(t + 1) * 128;

        // ---- ph0: MFMA(afA,bv0)->acc[0..3]; read afB <- A_k0 h1; stage A_k0(t+1)
        if (st) {
            __builtin_amdgcn_global_load_lds(AS1(gA[0] + koff), AS3(pt +    0 + ldst), 16, 0, 0);
            __builtin_amdgcn_global_load_lds(AS1(gA[1] + koff), AS3(pt + 8192 + ldst), 16, 0, 0);
        }
        asm volatile("s_barrier" ::: "memory");
        #pragma unroll
        for (int f = 0; f < 4; ++f)
            afB[f] = *(const bf16x8*)(pb + 4096 + aoff + f * 1024);
        MFMA16(afA, bv0, 0)

        // ---- ph1: MFMA(afB,bv0)->acc[4..7]; read afA <- A_k1 h0, bv1 <- B_k1; stage B_k0(t+1)
        if (st) {
            __builtin_amdgcn_global_load_lds(AS1(gB[0] + koff), AS3(pt + 32768 + ldst), 16, 0, 0);
            __builtin_amdgcn_global_load_lds(AS1(gB[1] + koff), AS3(pt + 40960 + ldst), 16, 0, 0);
            asm volatile("s_waitcnt vmcnt(4)" ::: "memory");
        } else {
            asm volatile("s_waitcnt vmcnt(0)" ::: "memory");
        }
        asm volatile("s_barrier" ::: "memory");
        #pragma unroll
        for (int f = 0; f < 4; ++f) {
            afA[f] = *(const bf16x8*)(pb + 16384 + aoff + f * 1024);   // A_k1 h0
            bv1[f] = *(const bf16x8*)(pb + 49152 + boff + f * 1024);   // B_k1
        }
        MFMA16(afB, bv0, 1)

        // ---- ph2: MFMA(afA,bv1)->acc[0..3]; read afB <- A_k1 h1; stage A_k1(t+1)
        if (st) {
            __builtin_amdgcn_global_load_lds(AS1(gA[0] + koff + 64), AS3(pt + 16384 + ldst), 16, 0, 0);
            __builtin_amdgcn_global_load_lds(AS1(gA[1] + koff + 64), AS3(pt + 24576 + ldst), 16, 0, 0);
        }
        asm volatile("s_barrier" ::: "memory");
        #pragma unroll
        for (int f = 0; f < 4; ++f)
            afB[f] = *(const bf16x8*)(pb + 16384 + 4096 + aoff + f * 1024);
        MFMA16(afA, bv1, 0)

        // ---- ph3: MFMA(afB,bv1)->acc[4..7]; read afA,bv0 <- NEXT tile (from pt); stage B_k1(t+1)
        if (st) {
            __builtin_amdgcn_global_load_lds(AS1(gB[0] + koff + 64), AS3(pt + 49152 + ldst), 16, 0, 0);
            __builtin_amdgcn_global_load_lds(AS1(gB[1] + koff + 64), AS3(pt + 57344 + ldst), 16, 0, 0);
            asm volatile("s_waitcnt vmcnt(4)" ::: "memory");
        }
        asm volatile("s_barrier" ::: "memory");
        if (st) {
            #pragma unroll
            for (int f = 0; f < 4; ++f) {
                afA[f] = *(const bf16x8*)(pt +     0 + aoff + f * 1024);   // A_k0(t+1) h0
                bv0[f] = *(const bf16x8*)(pt + 32768 + boff + f * 1024);   // B_k0(t+1)
            }
        }
        MFMA16(afB, bv1, 1)
    }
#undef MFMA16

    // epilogue: row = row0 + wm*128 + i*16 + (lane>>4)*4 + e ; col = col0 + wn*64 + j*16 + r16
    const int rb = (lane >> 4) * 4;
    #pragma unroll
    for (int i = 0; i < 8; ++i) {
        #pragma unroll
        for (int j = 0; j < 4; ++j) {
            const int cc = col0 + wn * 64 + j * 16 + r16;
            float badd = 0.f;
            if (MODE == 1) badd = bias[cc];
            #pragma unroll
            for (int e = 0; e < 4; ++e) {
                long row = row0 + wm * 128 + i * 16 + rb + e;
                float v = acc[i][j][e];
                if (MODE == 1) {
                    v += badd;
                    v = fmaxf(v, 0.f);
                    v = v * v;
                    ((bf16*)Cout)[row * ldc + cc] = __float2bfloat16(v);
                } else {
                    ((float*)Cout)[row * ldc + cc] = v;
                }
            }
        }
    }
}

// ---------------- glue: per-token gating / tiny einsums ----------------
// In:  g1,g2 [TOK][8][512] f32; Yl[:,0:4096]=x1 raw bf16; Yr[:,4096:8192]=x2 raw bf16
// Out: Yl = [x1*g1s | y12 | g1s]; Yr = [y21 | x2*g2s | g2s]  (all bf16)
#define GPAD 524   // 8-row pad: h-stride hits 8 distinct banks; 524*4%16==0
__global__ __launch_bounds__(256)
void glue(const float* __restrict__ g1, const float* __restrict__ g2,
          bf16* __restrict__ Yl, bf16* __restrict__ Yr)
{
    __shared__ __align__(16) float g1t[8 * GPAD];
    __shared__ __align__(16) float g2t[8 * GPAD];
    __shared__ float g1s[EE], g2s[EE];
    __shared__ float t1s[64], t2s[64];
    __shared__ float t1p[4][64], t2p[4][64];
    __shared__ __align__(16) bf16 x1t[FF], x2t[FF];

    const int t   = blockIdx.x;
    const int tid = threadIdx.x;
    const float* g1p = g1 + (size_t)t * FF;
    const float* g2p = g2 + (size_t)t * FF;
    bf16* ylp = Yl + (size_t)t * KCAT;
    bf16* yrp = Yr + (size_t)t * KCAT;

    #pragma unroll
    for (int c = 0; c < 4; ++c) {
        int idx4 = (c * 256 + tid) * 4;
        float4 v1 = *(const float4*)(g1p + idx4);
        float4 v2 = *(const float4*)(g2p + idx4);
        int h = idx4 >> 9, e = idx4 & 511;
        *(float4*)&g1t[h * GPAD + e] = v1;
        *(float4*)&g2t[h * GPAD + e] = v2;
    }
    #pragma unroll
    for (int c = 0; c < 2; ++c) {
        int idx8 = (c * 256 + tid) * 8;
        *(bf16x8*)&x1t[idx8] = *(const bf16x8*)(ylp + idx8);
        *(bf16x8*)&x2t[idx8] = *(const bf16x8*)(yrp + FF + idx8);
    }
    __syncthreads();

    #pragma unroll
    for (int c = 0; c < 2; ++c) {
        int e = c * 256 + tid;
        float s1 = 0.f, s2 = 0.f;
        #pragma unroll
        for (int h = 0; h < 8; ++h) { s1 += g1t[h * GPAD + e]; s2 += g2t[h * GPAD + e]; }
        g1s[e] = s1; g2s[e] = s2;
    }

    {   // t1[h,m] = sum_e x1[e,m]*g1[h,e] ; t2 likewise. 4-way partials.
        int o = tid & 63;
        int h = o & 7, m = o >> 3;
        int p = tid >> 6;
        float s1 = 0.f, s2 = 0.f;
        #pragma unroll 8
        for (int ii = 0; ii < 128; ++ii) {
            int e = p * 128 + ii;
            float xv1 = __bfloat162float(x1t[e * 8 + m]);
            float xv2 = __bfloat162float(x2t[e * 8 + m]);
            s1 += xv1 * g1t[h * GPAD + e];
            s2 += xv2 * g2t[h * GPAD + e];
        }
        t1p[p][o] = s1; t2p[p][o] = s2;
    }
    __syncthreads();
    if (tid < 64)       t1s[tid] = t1p[0][tid] + t1p[1][tid] + t1p[2][tid] + t1p[3][tid];
    else if (tid < 128) { int o = tid - 64; t2s[o] = t2p[0][o] + t2p[1][o] + t2p[2][o] + t2p[3][o]; }
    __syncthreads();

    #pragma unroll
    for (int c = 0; c < 2; ++c) {
        int f0 = (c * 256 + tid) * 8;
        int e  = f0 >> 3;
        float s1 = g1s[e], s2 = g2s[e];
        bf16x8 xa = *(const bf16x8*)&x1t[f0];
        bf16x8 xb = *(const bf16x8*)&x2t[f0];
        bf16x8 o1, o2;
        #pragma unroll
        for (int u = 0; u < 8; ++u) {
            o1[u] = (__bf16)((float)xa[u] * s1);
            o2[u] = (__bf16)((float)xb[u] * s2);
        }
        *(bf16x8*)(ylp + f0)      = o1;
        *(bf16x8*)(yrp + FF + f0) = o2;
    }
    #pragma unroll
    for (int c = 0; c < 2; ++c) {
        int f0 = (c * 256 + tid) * 8;
        int i  = f0 >> 3;
        bf16x8 o12v, o21v;
        #pragma unroll
        for (int m = 0; m < 8; ++m) {
            float s12 = 0.f, s21 = 0.f;
            #pragma unroll
            for (int h = 0; h < 8; ++h) {
                s12 += t2s[(m << 3) | h] * g1t[h * GPAD + i];
                s21 += t1s[(m << 3) | h] * g2t[h * GPAD + i];
            }
            o12v[m] = (__bf16)s12;
            o21v[m] = (__bf16)s21;
        }
        *(bf16x8*)(ylp + FF + f0) = o12v;
        *(bf16x8*)(yrp + f0)      = o21v;
    }
    {
        int e0 = tid * 2;
        ylp[2 * FF + e0]     = __float2bfloat16(g1s[e0]);
        ylp[2 * FF + e0 + 1] = __float2bfloat16(g1s[e0 + 1]);
        yrp[2 * FF + e0]     = __float2bfloat16(g2s[e0]);
        yrp[2 * FF + e0 + 1] = __float2bfloat16(g2s[e0 + 1]);
    }
}

// ---------------- launch ----------------

extern "C" void kernel_launch(void* const* d_in, const int* in_sizes, int n_in,
                              void* d_out, int out_size, void* d_ws, size_t ws_size,
                              hipStream_t stream) {
    const float* x    = (const float*)d_in[0];
    const float* g1   = (const float*)d_in[1];
    const float* g2   = (const float*)d_in[2];
    const float* u1_w = (const float*)d_in[3];
    const float* u1_b = (const float*)d_in[4];
    const float* u2_w = (const float*)d_in[5];
    const float* u2_b = (const float*)d_in[6];
    const float* v11  = (const float*)d_in[7];
    const float* v12  = (const float*)d_in[8];
    const float* v21  = (const float*)d_in[9];
    const float* v22  = (const float*)d_in[10];
    const float* b1   = (const float*)d_in[11];
    const float* b2   = (const float*)d_in[12];
    float* out = (float*)d_out;

    size_t off = 0;
    char* base = (char*)d_ws;
    auto take = [&](size_t bytes) { void* p = base + off; off += (bytes + 255) & ~(size_t)255; return p; };
    bf16* Xb  = (bf16*)take((size_t)TOK * DD * 2);
    bf16* U1b = (bf16*)take((size_t)FF * DD * 2);
    bf16* U2b = (bf16*)take((size_t)FF * DD * 2);
    bf16* Wl  = (bf16*)take((size_t)HALF * KCAT * 2);
    bf16* Wr  = (bf16*)take((size_t)HALF * KCAT * 2);
    bf16* Yl  = (bf16*)take((size_t)TOK * KCAT * 2);
    bf16* Yr  = (bf16*)take((size_t)TOK * KCAT * 2);

    // prep: x/u casts only (v/b packing rides inside the U-GEMM launch)
    prep_cvt<<<2048, 256, 0, stream>>>(x, u1_w, u2_w, Xb, U1b, U2b);

    // fused U-GEMMs (+256 piggyback pack blocks): x1raw -> Yl[:,0:4096],
    // x2raw -> Yr[:,4096:8192] (relu^2, bf16); v/b -> Wl/Wr
    gemmP<1><<<2 * (TOK / 256) * (FF / 256) + 256, 512, 0, stream>>>(
        Xb, U1b, u1_b, Yl,
        Xb, U2b, u2_b, Yr + FF,
        TOK / 256, FF / 256, DD, KCAT,
        v11, v12, v21, v22, b1, b2, Wl, Wr);

    // gating / tiny einsums
    glue<<<TOK, 256, 0, stream>>>(g1, g2, Yl, Yr);

    // fused V-GEMMs: out[:,0:1024] = Yl @ Wl^T ; out[:,1024:2048] = Yr @ Wr^T  (fp32)
    gemmP<0><<<2 * (TOK / 256) * (HALF / 256), 512, 0, stream>>>(
        Yl, Wl, nullptr, out,
        Yr, Wr, nullptr, out + HALF,
        TOK / 256, HALF / 256, KCAT, DD,
        nullptr, nullptr, nullptr, nullptr, nullptr, nullptr, nullptr, nullptr);
}

// Round 14
// 679.794 us; speedup vs baseline: 1.2052x; 1.0064x over previous
//
#include <hip/hip_runtime.h>
#include <hip/hip_bf16.h>

// MonetMoVDE: B=4 T=2048 D=2048 H=8 E=512 M=8, F=4096, HALF=1024
#define TOK   8192   // B*T
#define DD    2048
#define FF    4096
#define EE    512
#define HALF  1024
#define KCAT  8704   // F + F + E  (concat K for V-GEMMs, 8704 = 136*64)

typedef __bf16 bf16x8 __attribute__((ext_vector_type(8)));
typedef __bf16 bf16x4 __attribute__((ext_vector_type(4)));
typedef float  f32x4  __attribute__((ext_vector_type(4)));
using bf16 = __hip_bfloat16;

#define AS1(p) ((const __attribute__((address_space(1))) void*)(p))
#define AS3(p) ((__attribute__((address_space(3))) void*)(p))

// ---------------- prep: x/u1/u2 f32->bf16 cvt only ----------------
#define PR0 4194304u
#define PR1 6291456u
#define PR2 8388608u
__global__ __launch_bounds__(256)
void prep_cvt(const float* __restrict__ x, const float* __restrict__ u1_w,
              const float* __restrict__ u2_w,
              bf16* __restrict__ Xb, bf16* __restrict__ U1b, bf16* __restrict__ U2b)
{
    const unsigned stride = gridDim.x * blockDim.x;
    for (unsigned i = blockIdx.x * blockDim.x + threadIdx.x; i < PR2; i += stride) {
        const float* src; bf16* dst; unsigned s;
        if (i < PR0)      { s = i;        src = x;    dst = Xb;  }
        else if (i < PR1) { s = i - PR0;  src = u1_w; dst = U1b; }
        else              { s = i - PR1;  src = u2_w; dst = U2b; }
        float4 v = ((const float4*)src)[s];
        bf16x4 o;
        o[0] = (__bf16)v.x; o[1] = (__bf16)v.y; o[2] = (__bf16)v.z; o[3] = (__bf16)v.w;
        ((bf16x4*)dst)[s] = o;
    }
}

// ---------------- GEMM: C[m,n] = sum_k A[m,k] * Bw[n,k] ----------------
// r6/r13 structure with FENCE-MINIMIZED barriers: non-gate barriers are
// __builtin_amdgcn_s_barrier() (no "memory" clobber -> compiler may schedule
// ds_reads/MFMA across phase boundaries); ONLY the two counted vmcnt(4)
// gates per K-tile carry the "memory" clobber (semantic fences: gload_lds
// cannot cross them, FIFO ledger + ph3 read-ahead gating preserved).
// 256x256 tile, BK=64, 8 waves (2Mx4N), 16x16x32 MFMA, per-wave C 128x64.
// LDS buffer (64KB) = 4 planes of 16KB: A_k0 @0, A_k1 @16K, B_k0 @32K, B_k1 @48K.
// Plane = 256 rows x 64B, swizzle byte ^= (((row>>1)&3)<<4) - proven zero-conflict.
// MODE 1 carries 256 piggyback pack blocks (raw blockIdx >= 2*npg, LDS-free).
// Fused dual-GEMM; MODE 0: fp32 store, MODE 1: relu(z+bias)^2 -> bf16 store.
template<int MODE>
__global__ __launch_bounds__(512, 2)
void gemmP(const bf16* __restrict__ A0, const bf16* __restrict__ B0,
           const float* __restrict__ bias0, void* __restrict__ C0,
           const bf16* __restrict__ A1, const bf16* __restrict__ B1,
           const float* __restrict__ bias1, void* __restrict__ C1,
           int nbm, int nbn, int K, int ldc,
           const float* __restrict__ xv11, const float* __restrict__ xv12,
           const float* __restrict__ xv21, const float* __restrict__ xv22,
           const float* __restrict__ xb1, const float* __restrict__ xb2,
           bf16* __restrict__ xWl, bf16* __restrict__ xWr)
{
    __shared__ __align__(16) char smem[131072];   // 2 x 64KB
    const int tid  = threadIdx.x;
    const int npg  = nbm * nbn;

    if (MODE == 1 && blockIdx.x >= (unsigned)(2 * npg)) {
        // ---- piggyback pack block (no LDS, no barriers) ----
        const unsigned lane_g = (blockIdx.x - 2 * npg) * 512u + tid;   // [0, 131072)
        #pragma unroll 4
        for (int k = 0; k < 32; ++k) {                                  // 4,194,304 float4 slots
            unsigned w = lane_g + (unsigned)k * 131072u;
            const bool left = w < 2097152u;
            unsigned s = left ? w : w - 2097152u;
            unsigned n = s >> 11, j = s & 2047u;
            const float* vs = left ? (j < 1024u ? xv11 : xv12) : (j < 1024u ? xv21 : xv22);
            unsigned jj = (j < 1024u) ? j : (j - 1024u);
            float4 v = *(const float4*)(vs + (size_t)n * FF + jj * 4);
            bf16x4 o;
            o[0] = (__bf16)v.x; o[1] = (__bf16)v.y; o[2] = (__bf16)v.z; o[3] = (__bf16)v.w;
            bf16* wb = left ? xWl : xWr;
            *(bf16x4*)(wb + (size_t)n * KCAT + ((j < 1024u) ? 0 : FF) + jj * 4) = o;
        }
        #pragma unroll 2
        for (int k = 0; k < 8; ++k) {                                   // 1,048,576 bmat scalars
            unsigned w = lane_g + (unsigned)k * 131072u;
            const bool left = w < 524288u;
            unsigned r = left ? w : w - 524288u;
            unsigned n = r >> 9, e = r & 511u;
            const float* bm = left ? xb1 : xb2;
            bf16* wb = left ? xWl : xWr;
            wb[(size_t)n * KCAT + 2 * FF + e] = __float2bfloat16(bm[(size_t)e * HALF + n]);
        }
        return;
    }

    const int lane = tid & 63;
    const int wid  = tid >> 6;
    const int wm = wid >> 2, wn = wid & 3;
    const int r16 = lane & 15, kb = lane >> 4;

    int bid = blockIdx.x;
    {   // bijective XCD swizzle (m204) over the GEMM blocks only
        int nwg = 2 * npg;
        int q = nwg >> 3, r = nwg & 7;
        int xcd = bid & 7, idx = bid >> 3;
        bid = (xcd < r ? xcd * (q + 1) : r * (q + 1) + (xcd - r) * q) + idx;
    }
    const int g   = bid / npg;
    const int lb  = bid - g * npg;
    const int bm = lb / nbn, bn = lb - bm * nbn;

    const bf16*  A    = g ? A1 : A0;
    const bf16*  Bw   = g ? B1 : B0;
    const float* bias = g ? bias1 : bias0;
    char* Cout = (char*)(g ? C1 : C0);

    const long row0 = (long)bm * 256;
    const int  col0 = bn * 256;
    const int  nt   = K >> 6;

    // staging sources (pre-swizzled; involution) + linear LDS dest offset
    const char* gA[2]; const char* gB[2];
    #pragma unroll
    for (int l = 0; l < 2; ++l) {
        const uint32_t S = (uint32_t)(l * 512 + tid) * 16;   // byte slot in 16KB plane
        const int r  = (int)(S >> 6);                        // plane row 0..255
        const int cb = (int)((S & 63) ^ ((uint32_t)((r >> 1) & 3) << 4));
        gA[l] = (const char*)A  + (row0 + r) * (long)K * 2 + cb;
        gB[l] = (const char*)Bw + (long)(col0 + r) * K * 2 + cb;
    }
    const uint32_t ldst = (uint32_t)(tid & ~63) * 16;        // + l*8192 + plane base

    // per-lane read base offsets within a plane (swizzled; proven zero-conflict)
    const uint32_t swz  = ((uint32_t)(r16 >> 1) & 3u) << 4;
    const uint32_t aoff = (uint32_t)((wm * 128 + r16) * 64 + kb * 16) ^ swz;  // +4096 for row-half1, +fi*1024
    const uint32_t boff = (uint32_t)((wn * 64  + r16) * 64 + kb * 16) ^ swz;  // +fj*1024

    f32x4 acc[8][4];
    #pragma unroll
    for (int i = 0; i < 8; ++i)
        #pragma unroll
        for (int j = 0; j < 4; ++j)
            acc[i][j] = (f32x4){0.f, 0.f, 0.f, 0.f};

    // prologue: stage all 4 planes of tile 0 into buf0 (order A_k0,B_k0,A_k1,B_k1)
    __builtin_amdgcn_global_load_lds(AS1(gA[0]),      AS3(smem +     0 + ldst), 16, 0, 0);
    __builtin_amdgcn_global_load_lds(AS1(gA[1]),      AS3(smem +  8192 + ldst), 16, 0, 0);
    __builtin_amdgcn_global_load_lds(AS1(gB[0]),      AS3(smem + 32768 + ldst), 16, 0, 0);
    __builtin_amdgcn_global_load_lds(AS1(gB[1]),      AS3(smem + 40960 + ldst), 16, 0, 0);
    __builtin_amdgcn_global_load_lds(AS1(gA[0] + 64), AS3(smem + 16384 + ldst), 16, 0, 0);
    __builtin_amdgcn_global_load_lds(AS1(gA[1] + 64), AS3(smem + 24576 + ldst), 16, 0, 0);
    __builtin_amdgcn_global_load_lds(AS1(gB[0] + 64), AS3(smem + 49152 + ldst), 16, 0, 0);
    __builtin_amdgcn_global_load_lds(AS1(gB[1] + 64), AS3(smem + 57344 + ldst), 16, 0, 0);
    // gate planes A_k0,B_k0 of tile 0 (first 4 loads), then preload ph0 frags
    asm volatile("s_waitcnt vmcnt(4)" ::: "memory");
    __builtin_amdgcn_s_barrier();

    bf16x8 afA[4], afB[4], bv0[4], bv1[4];
    #pragma unroll
    for (int f = 0; f < 4; ++f) {
        afA[f] = *(const bf16x8*)(smem +     0 + aoff + f * 1024);   // A_k0 h0
        bv0[f] = *(const bf16x8*)(smem + 32768 + boff + f * 1024);   // B_k0
    }

#define MFMA16(AF, BV, IH)                                                              \
    __builtin_amdgcn_s_setprio(1);                                                      \
    _Pragma("unroll")                                                                   \
    for (int fi = 0; fi < 4; ++fi) {                                                    \
        acc[(IH)*4+fi][0] = __builtin_amdgcn_mfma_f32_16x16x32_bf16(AF[fi], BV[0], acc[(IH)*4+fi][0], 0, 0, 0); \
        acc[(IH)*4+fi][1] = __builtin_amdgcn_mfma_f32_16x16x32_bf16(AF[fi], BV[1], acc[(IH)*4+fi][1], 0, 0, 0); \
        acc[(IH)*4+fi][2] = __builtin_amdgcn_mfma_f32_16x16x32_bf16(AF[fi], BV[2], acc[(IH)*4+fi][2], 0, 0, 0); \
        acc[(IH)*4+fi][3] = __builtin_amdgcn_mfma_f32_16x16x32_bf16(AF[fi], BV[3], acc[(IH)*4+fi][3], 0, 0, 0); \
    }                                                                                   \
    __builtin_amdgcn_s_setprio(0);

    for (int t = 0; t < nt; ++t) {
        const char* pb = smem + (t & 1) * 65536;
        char*       pt = smem + ((t + 1) & 1) * 65536;
        const bool  st = (t + 1 < nt);
        const long  koff = (long)(t + 1) * 128;

        // ---- ph0: MFMA(afA,bv0)->acc[0..3]; read afB <- A_k0 h1; stage A_k0(t+1)
        if (st) {
            __builtin_amdgcn_global_load_lds(AS1(gA[0] + koff), AS3(pt +    0 + ldst), 16, 0, 0);
            __builtin_amdgcn_global_load_lds(AS1(gA[1] + koff), AS3(pt + 8192 + ldst), 16, 0, 0);
        }
        __builtin_amdgcn_s_barrier();    // no compiler fence: reads of pb may float
        #pragma unroll
        for (int f = 0; f < 4; ++f)
            afB[f] = *(const bf16x8*)(pb + 4096 + aoff + f * 1024);
        MFMA16(afA, bv0, 0)

        // ---- ph1: MFMA(afB,bv0)->acc[4..7]; read afA <- A_k1 h0, bv1 <- B_k1; stage B_k0(t+1)
        if (st) {
            __builtin_amdgcn_global_load_lds(AS1(gB[0] + koff), AS3(pt + 32768 + ldst), 16, 0, 0);
            __builtin_amdgcn_global_load_lds(AS1(gB[1] + koff), AS3(pt + 40960 + ldst), 16, 0, 0);
            asm volatile("s_waitcnt vmcnt(4)" ::: "memory");   // GATE: retires A_k1(t),B_k1(t)
        } else {
            asm volatile("s_waitcnt vmcnt(0)" ::: "memory");
        }
        __builtin_amdgcn_s_barrier();
        #pragma unroll
        for (int f = 0; f < 4; ++f) {
            afA[f] = *(const bf16x8*)(pb + 16384 + aoff + f * 1024);   // A_k1 h0
            bv1[f] = *(const bf16x8*)(pb + 49152 + boff + f * 1024);   // B_k1
        }
        MFMA16(afB, bv0, 1)

        // ---- ph2: MFMA(afA,bv1)->acc[0..3]; read afB <- A_k1 h1; stage A_k1(t+1)
        if (st) {
            __builtin_amdgcn_global_load_lds(AS1(gA[0] + koff + 64), AS3(pt + 16384 + ldst), 16, 0, 0);
            __builtin_amdgcn_global_load_lds(AS1(gA[1] + koff + 64), AS3(pt + 24576 + ldst), 16, 0, 0);
        }
        __builtin_amdgcn_s_barrier();
        #pragma unroll
        for (int f = 0; f < 4; ++f)
            afB[f] = *(const bf16x8*)(pb + 16384 + 4096 + aoff + f * 1024);
        MFMA16(afA, bv1, 0)

        // ---- ph3: MFMA(afB,bv1)->acc[4..7]; read afA,bv0 <- NEXT tile (from pt); stage B_k1(t+1)
        if (st) {
            __builtin_amdgcn_global_load_lds(AS1(gB[0] + koff + 64), AS3(pt + 49152 + ldst), 16, 0, 0);
            __builtin_amdgcn_global_load_lds(AS1(gB[1] + koff + 64), AS3(pt + 57344 + ldst), 16, 0, 0);
            asm volatile("s_waitcnt vmcnt(4)" ::: "memory");   // GATE: retires A_k0(t+1),B_k0(t+1)
        }
        __builtin_amdgcn_s_barrier();
        if (st) {
            #pragma unroll
            for (int f = 0; f < 4; ++f) {
                afA[f] = *(const bf16x8*)(pt +     0 + aoff + f * 1024);   // A_k0(t+1) h0
                bv0[f] = *(const bf16x8*)(pt + 32768 + boff + f * 1024);   // B_k0(t+1)
            }
        }
        MFMA16(afB, bv1, 1)
    }
#undef MFMA16

    // epilogue: row = row0 + wm*128 + i*16 + (lane>>4)*4 + e ; col = col0 + wn*64 + j*16 + r16
    const int rb = (lane >> 4) * 4;
    #pragma unroll
    for (int i = 0; i < 8; ++i) {
        #pragma unroll
        for (int j = 0; j < 4; ++j) {
            const int cc = col0 + wn * 64 + j * 16 + r16;
            float badd = 0.f;
            if (MODE == 1) badd = bias[cc];
            #pragma unroll
            for (int e = 0; e < 4; ++e) {
                long row = row0 + wm * 128 + i * 16 + rb + e;
                float v = acc[i][j][e];
                if (MODE == 1) {
                    v += badd;
                    v = fmaxf(v, 0.f);
                    v = v * v;
                    ((bf16*)Cout)[row * ldc + cc] = __float2bfloat16(v);
                } else {
                    ((float*)Cout)[row * ldc + cc] = v;
                }
            }
        }
    }
}

// ---------------- glue: per-token gating / tiny einsums ----------------
// In:  g1,g2 [TOK][8][512] f32; Yl[:,0:4096]=x1 raw bf16; Yr[:,4096:8192]=x2 raw bf16
// Out: Yl = [x1*g1s | y12 | g1s]; Yr = [y21 | x2*g2s | g2s]  (all bf16)
#define GPAD 524   // 8-row pad: h-stride hits 8 distinct banks; 524*4%16==0
__global__ __launch_bounds__(256)
void glue(const float* __restrict__ g1, const float* __restrict__ g2,
          bf16* __restrict__ Yl, bf16* __restrict__ Yr)
{
    __shared__ __align__(16) float g1t[8 * GPAD];
    __shared__ __align__(16) float g2t[8 * GPAD];
    __shared__ float g1s[EE], g2s[EE];
    __shared__ float t1s[64], t2s[64];
    __shared__ float t1p[4][64], t2p[4][64];
    __shared__ __align__(16) bf16 x1t[FF], x2t[FF];

    const int t   = blockIdx.x;
    const int tid = threadIdx.x;
    const float* g1p = g1 + (size_t)t * FF;
    const float* g2p = g2 + (size_t)t * FF;
    bf16* ylp = Yl + (size_t)t * KCAT;
    bf16* yrp = Yr + (size_t)t * KCAT;

    #pragma unroll
    for (int c = 0; c < 4; ++c) {
        int idx4 = (c * 256 + tid) * 4;
        float4 v1 = *(const float4*)(g1p + idx4);
        float4 v2 = *(const float4*)(g2p + idx4);
        int h = idx4 >> 9, e = idx4 & 511;
        *(float4*)&g1t[h * GPAD + e] = v1;
        *(float4*)&g2t[h * GPAD + e] = v2;
    }
    #pragma unroll
    for (int c = 0; c < 2; ++c) {
        int idx8 = (c * 256 + tid) * 8;
        *(bf16x8*)&x1t[idx8] = *(const bf16x8*)(ylp + idx8);
        *(bf16x8*)&x2t[idx8] = *(const bf16x8*)(yrp + FF + idx8);
    }
    __syncthreads();

    #pragma unroll
    for (int c = 0; c < 2; ++c) {
        int e = c * 256 + tid;
        float s1 = 0.f, s2 = 0.f;
        #pragma unroll
        for (int h = 0; h < 8; ++h) { s1 += g1t[h * GPAD + e]; s2 += g2t[h * GPAD + e]; }
        g1s[e] = s1; g2s[e] = s2;
    }

    {   // t1[h,m] = sum_e x1[e,m]*g1[h,e] ; t2 likewise. 4-way partials.
        int o = tid & 63;
        int h = o & 7, m = o >> 3;
        int p = tid >> 6;
        float s1 = 0.f, s2 = 0.f;
        #pragma unroll 8
        for (int ii = 0; ii < 128; ++ii) {
            int e = p * 128 + ii;
            float xv1 = __bfloat162float(x1t[e * 8 + m]);
            float xv2 = __bfloat162float(x2t[e * 8 + m]);
            s1 += xv1 * g1t[h * GPAD + e];
            s2 += xv2 * g2t[h * GPAD + e];
        }
        t1p[p][o] = s1; t2p[p][o] = s2;
    }
    __syncthreads();
    if (tid < 64)       t1s[tid] = t1p[0][tid] + t1p[1][tid] + t1p[2][tid] + t1p[3][tid];
    else if (tid < 128) { int o = tid - 64; t2s[o] = t2p[0][o] + t2p[1][o] + t2p[2][o] + t2p[3][o]; }
    __syncthreads();

    #pragma unroll
    for (int c = 0; c < 2; ++c) {
        int f0 = (c * 256 + tid) * 8;
        int e  = f0 >> 3;
        float s1 = g1s[e], s2 = g2s[e];
        bf16x8 xa = *(const bf16x8*)&x1t[f0];
        bf16x8 xb = *(const bf16x8*)&x2t[f0];
        bf16x8 o1, o2;
        #pragma unroll
        for (int u = 0; u < 8; ++u) {
            o1[u] = (__bf16)((float)xa[u] * s1);
            o2[u] = (__bf16)((float)xb[u] * s2);
        }
        *(bf16x8*)(ylp + f0)      = o1;
        *(bf16x8*)(yrp + FF + f0) = o2;
    }
    #pragma unroll
    for (int c = 0; c < 2; ++c) {
        int f0 = (c * 256 + tid) * 8;
        int i  = f0 >> 3;
        bf16x8 o12v, o21v;
        #pragma unroll
        for (int m = 0; m < 8; ++m) {
            float s12 = 0.f, s21 = 0.f;
            #pragma unroll
            for (int h = 0; h < 8; ++h) {
                s12 += t2s[(m << 3) | h] * g1t[h * GPAD + i];
                s21 += t1s[(m << 3) | h] * g2t[h * GPAD + i];
            }
            o12v[m] = (__bf16)s12;
            o21v[m] = (__bf16)s21;
        }
        *(bf16x8*)(ylp + FF + f0) = o12v;
        *(bf16x8*)(yrp + f0)      = o21v;
    }
    {
        int e0 = tid * 2;
        ylp[2 * FF + e0]     = __float2bfloat16(g1s[e0]);
        ylp[2 * FF + e0 + 1] = __float2bfloat16(g1s[e0 + 1]);
        yrp[2 * FF + e0]     = __float2bfloat16(g2s[e0]);
        yrp[2 * FF + e0 + 1] = __float2bfloat16(g2s[e0 + 1]);
    }
}

// ---------------- launch ----------------

extern "C" void kernel_launch(void* const* d_in, const int* in_sizes, int n_in,
                              void* d_out, int out_size, void* d_ws, size_t ws_size,
                              hipStream_t stream) {
    const float* x    = (const float*)d_in[0];
    const float* g1   = (const float*)d_in[1];
    const float* g2   = (const float*)d_in[2];
    const float* u1_w = (const float*)d_in[3];
    const float* u1_b = (const float*)d_in[4];
    const float* u2_w = (const float*)d_in[5];
    const float* u2_b = (const float*)d_in[6];
    const float* v11  = (const float*)d_in[7];
    const float* v12  = (const float*)d_in[8];
    const float* v21  = (const float*)d_in[9];
    const float* v22  = (const float*)d_in[10];
    const float* b1   = (const float*)d_in[11];
    const float* b2   = (const float*)d_in[12];
    float* out = (float*)d_out;

    size_t off = 0;
    char* base = (char*)d_ws;
    auto take = [&](size_t bytes) { void* p = base + off; off += (bytes + 255) & ~(size_t)255; return p; };
    bf16* Xb  = (bf16*)take((size_t)TOK * DD * 2);
    bf16* U1b = (bf16*)take((size_t)FF * DD * 2);
    bf16* U2b = (bf16*)take((size_t)FF * DD * 2);
    bf16* Wl  = (bf16*)take((size_t)HALF * KCAT * 2);
    bf16* Wr  = (bf16*)take((size_t)HALF * KCAT * 2);
    bf16* Yl  = (bf16*)take((size_t)TOK * KCAT * 2);
    bf16* Yr  = (bf16*)take((size_t)TOK * KCAT * 2);

    // prep: x/u casts only (v/b packing rides inside the U-GEMM launch)
    prep_cvt<<<2048, 256, 0, stream>>>(x, u1_w, u2_w, Xb, U1b, U2b);

    // fused U-GEMMs (+256 piggyback pack blocks): x1raw -> Yl[:,0:4096],
    // x2raw -> Yr[:,4096:8192] (relu^2, bf16); v/b -> Wl/Wr
    gemmP<1><<<2 * (TOK / 256) * (FF / 256) + 256, 512, 0, stream>>>(
        Xb, U1b, u1_b, Yl,
        Xb, U2b, u2_b, Yr + FF,
        TOK / 256, FF / 256, DD, KCAT,
        v11, v12, v21, v22, b1, b2, Wl, Wr);

    // gating / tiny einsums
    glue<<<TOK, 256, 0, stream>>>(g1, g2, Yl, Yr);

    // fused V-GEMMs: out[:,0:1024] = Yl @ Wl^T ; out[:,1024:2048] = Yr @ Wr^T  (fp32)
    gemmP<0><<<2 * (TOK / 256) * (HALF / 256), 512, 0, stream>>>(
        Yl, Wl, nullptr, out,
        Yr, Wr, nullptr, out + HALF,
        TOK / 256, HALF / 256, KCAT, DD,
        nullptr, nullptr, nullptr, nullptr, nullptr, nullptr, nullptr, nullptr);
}

// Round 15
// 677.009 us; speedup vs baseline: 1.2101x; 1.0041x over previous
//
#include <hip/hip_runtime.h>
#include <hip/hip_bf16.h>

// MonetMoVDE: B=4 T=2048 D=2048 H=8 E=512 M=8, F=4096, HALF=1024
#define TOK   8192   // B*T
#define DD    2048
#define FF    4096
#define EE    512
#define HALF  1024
#define KCAT  8704   // F + F + E  (concat K for V-GEMMs, 8704 = 136*64)

typedef __bf16 bf16x8 __attribute__((ext_vector_type(8)));
typedef __bf16 bf16x4 __attribute__((ext_vector_type(4)));
typedef float  f32x4  __attribute__((ext_vector_type(4)));
using bf16 = __hip_bfloat16;

#define AS1(p) ((const __attribute__((address_space(1))) void*)(p))
#define AS3(p) ((__attribute__((address_space(3))) void*)(p))

// ---------------- prep: x/u1/u2 f32->bf16 cvt only ----------------
#define PR0 4194304u
#define PR1 6291456u
#define PR2 8388608u
__global__ __launch_bounds__(256)
void prep_cvt(const float* __restrict__ x, const float* __restrict__ u1_w,
              const float* __restrict__ u2_w,
              bf16* __restrict__ Xb, bf16* __restrict__ U1b, bf16* __restrict__ U2b)
{
    const unsigned stride = gridDim.x * blockDim.x;
    for (unsigned i = blockIdx.x * blockDim.x + threadIdx.x; i < PR2; i += stride) {
        const float* src; bf16* dst; unsigned s;
        if (i < PR0)      { s = i;        src = x;    dst = Xb;  }
        else if (i < PR1) { s = i - PR0;  src = u1_w; dst = U1b; }
        else              { s = i - PR1;  src = u2_w; dst = U2b; }
        float4 v = ((const float4*)src)[s];
        bf16x4 o;
        o[0] = (__bf16)v.x; o[1] = (__bf16)v.y; o[2] = (__bf16)v.z; o[3] = (__bf16)v.w;
        ((bf16x4*)dst)[s] = o;
    }
}

// ---------------- GEMM: C[m,n] = sum_k A[m,k] * Bw[n,k] ----------------
// r14 structure, setprio REMOVED (m190: setprio hurts lockstep GEMM; mine is
// effectively lockstep per 7-variant evidence). Fence-minimized barriers kept.
// 256x256 tile, BK=64, 8 waves (2Mx4N), 16x16x32 MFMA, per-wave C 128x64.
// LDS buffer (64KB) = 4 planes of 16KB: A_k0 @0, A_k1 @16K, B_k0 @32K, B_k1 @48K.
// Plane = 256 rows x 64B, swizzle byte ^= (((row>>1)&3)<<4) - proven zero-conflict.
// MODE 1 carries 256 piggyback pack blocks (raw blockIdx >= 2*npg, LDS-free).
// Fused dual-GEMM; MODE 0: fp32 store, MODE 1: relu(z+bias)^2 -> bf16 store.
template<int MODE>
__global__ __launch_bounds__(512, 2)
void gemmP(const bf16* __restrict__ A0, const bf16* __restrict__ B0,
           const float* __restrict__ bias0, void* __restrict__ C0,
           const bf16* __restrict__ A1, const bf16* __restrict__ B1,
           const float* __restrict__ bias1, void* __restrict__ C1,
           int nbm, int nbn, int K, int ldc,
           const float* __restrict__ xv11, const float* __restrict__ xv12,
           const float* __restrict__ xv21, const float* __restrict__ xv22,
           const float* __restrict__ xb1, const float* __restrict__ xb2,
           bf16* __restrict__ xWl, bf16* __restrict__ xWr)
{
    __shared__ __align__(16) char smem[131072];   // 2 x 64KB
    const int tid  = threadIdx.x;
    const int npg  = nbm * nbn;

    if (MODE == 1 && blockIdx.x >= (unsigned)(2 * npg)) {
        // ---- piggyback pack block (no LDS, no barriers) ----
        const unsigned lane_g = (blockIdx.x - 2 * npg) * 512u + tid;   // [0, 131072)
        #pragma unroll 4
        for (int k = 0; k < 32; ++k) {                                  // 4,194,304 float4 slots
            unsigned w = lane_g + (unsigned)k * 131072u;
            const bool left = w < 2097152u;
            unsigned s = left ? w : w - 2097152u;
            unsigned n = s >> 11, j = s & 2047u;
            const float* vs = left ? (j < 1024u ? xv11 : xv12) : (j < 1024u ? xv21 : xv22);
            unsigned jj = (j < 1024u) ? j : (j - 1024u);
            float4 v = *(const float4*)(vs + (size_t)n * FF + jj * 4);
            bf16x4 o;
            o[0] = (__bf16)v.x; o[1] = (__bf16)v.y; o[2] = (__bf16)v.z; o[3] = (__bf16)v.w;
            bf16* wb = left ? xWl : xWr;
            *(bf16x4*)(wb + (size_t)n * KCAT + ((j < 1024u) ? 0 : FF) + jj * 4) = o;
        }
        #pragma unroll 2
        for (int k = 0; k < 8; ++k) {                                   // 1,048,576 bmat scalars
            unsigned w = lane_g + (unsigned)k * 131072u;
            const bool left = w < 524288u;
            unsigned r = left ? w : w - 524288u;
            unsigned n = r >> 9, e = r & 511u;
            const float* bm = left ? xb1 : xb2;
            bf16* wb = left ? xWl : xWr;
            wb[(size_t)n * KCAT + 2 * FF + e] = __float2bfloat16(bm[(size_t)e * HALF + n]);
        }
        return;
    }

    const int lane = tid & 63;
    const int wid  = tid >> 6;
    const int wm = wid >> 2, wn = wid & 3;
    const int r16 = lane & 15, kb = lane >> 4;

    int bid = blockIdx.x;
    {   // bijective XCD swizzle (m204) over the GEMM blocks only
        int nwg = 2 * npg;
        int q = nwg >> 3, r = nwg & 7;
        int xcd = bid & 7, idx = bid >> 3;
        bid = (xcd < r ? xcd * (q + 1) : r * (q + 1) + (xcd - r) * q) + idx;
    }
    const int g   = bid / npg;
    const int lb  = bid - g * npg;
    const int bm = lb / nbn, bn = lb - bm * nbn;

    const bf16*  A    = g ? A1 : A0;
    const bf16*  Bw   = g ? B1 : B0;
    const float* bias = g ? bias1 : bias0;
    char* Cout = (char*)(g ? C1 : C0);

    const long row0 = (long)bm * 256;
    const int  col0 = bn * 256;
    const int  nt   = K >> 6;

    // staging sources (pre-swizzled; involution) + linear LDS dest offset
    const char* gA[2]; const char* gB[2];
    #pragma unroll
    for (int l = 0; l < 2; ++l) {
        const uint32_t S = (uint32_t)(l * 512 + tid) * 16;   // byte slot in 16KB plane
        const int r  = (int)(S >> 6);                        // plane row 0..255
        const int cb = (int)((S & 63) ^ ((uint32_t)((r >> 1) & 3) << 4));
        gA[l] = (const char*)A  + (row0 + r) * (long)K * 2 + cb;
        gB[l] = (const char*)Bw + (long)(col0 + r) * K * 2 + cb;
    }
    const uint32_t ldst = (uint32_t)(tid & ~63) * 16;        // + l*8192 + plane base

    // per-lane read base offsets within a plane (swizzled; proven zero-conflict)
    const uint32_t swz  = ((uint32_t)(r16 >> 1) & 3u) << 4;
    const uint32_t aoff = (uint32_t)((wm * 128 + r16) * 64 + kb * 16) ^ swz;  // +4096 for row-half1, +fi*1024
    const uint32_t boff = (uint32_t)((wn * 64  + r16) * 64 + kb * 16) ^ swz;  // +fj*1024

    f32x4 acc[8][4];
    #pragma unroll
    for (int i = 0; i < 8; ++i)
        #pragma unroll
        for (int j = 0; j < 4; ++j)
            acc[i][j] = (f32x4){0.f, 0.f, 0.f, 0.f};

    // prologue: stage all 4 planes of tile 0 into buf0 (order A_k0,B_k0,A_k1,B_k1)
    __builtin_amdgcn_global_load_lds(AS1(gA[0]),      AS3(smem +     0 + ldst), 16, 0, 0);
    __builtin_amdgcn_global_load_lds(AS1(gA[1]),      AS3(smem +  8192 + ldst), 16, 0, 0);
    __builtin_amdgcn_global_load_lds(AS1(gB[0]),      AS3(smem + 32768 + ldst), 16, 0, 0);
    __builtin_amdgcn_global_load_lds(AS1(gB[1]),      AS3(smem + 40960 + ldst), 16, 0, 0);
    __builtin_amdgcn_global_load_lds(AS1(gA[0] + 64), AS3(smem + 16384 + ldst), 16, 0, 0);
    __builtin_amdgcn_global_load_lds(AS1(gA[1] + 64), AS3(smem + 24576 + ldst), 16, 0, 0);
    __builtin_amdgcn_global_load_lds(AS1(gB[0] + 64), AS3(smem + 49152 + ldst), 16, 0, 0);
    __builtin_amdgcn_global_load_lds(AS1(gB[1] + 64), AS3(smem + 57344 + ldst), 16, 0, 0);
    // gate planes A_k0,B_k0 of tile 0 (first 4 loads), then preload ph0 frags
    asm volatile("s_waitcnt vmcnt(4)" ::: "memory");
    __builtin_amdgcn_s_barrier();

    bf16x8 afA[4], afB[4], bv0[4], bv1[4];
    #pragma unroll
    for (int f = 0; f < 4; ++f) {
        afA[f] = *(const bf16x8*)(smem +     0 + aoff + f * 1024);   // A_k0 h0
        bv0[f] = *(const bf16x8*)(smem + 32768 + boff + f * 1024);   // B_k0
    }

#define MFMA16(AF, BV, IH)                                                              \
    _Pragma("unroll")                                                                   \
    for (int fi = 0; fi < 4; ++fi) {                                                    \
        acc[(IH)*4+fi][0] = __builtin_amdgcn_mfma_f32_16x16x32_bf16(AF[fi], BV[0], acc[(IH)*4+fi][0], 0, 0, 0); \
        acc[(IH)*4+fi][1] = __builtin_amdgcn_mfma_f32_16x16x32_bf16(AF[fi], BV[1], acc[(IH)*4+fi][1], 0, 0, 0); \
        acc[(IH)*4+fi][2] = __builtin_amdgcn_mfma_f32_16x16x32_bf16(AF[fi], BV[2], acc[(IH)*4+fi][2], 0, 0, 0); \
        acc[(IH)*4+fi][3] = __builtin_amdgcn_mfma_f32_16x16x32_bf16(AF[fi], BV[3], acc[(IH)*4+fi][3], 0, 0, 0); \
    }

    for (int t = 0; t < nt; ++t) {
        const char* pb = smem + (t & 1) * 65536;
        char*       pt = smem + ((t + 1) & 1) * 65536;
        const bool  st = (t + 1 < nt);
        const long  koff = (long)(t + 1) * 128;

        // ---- ph0: MFMA(afA,bv0)->acc[0..3]; read afB <- A_k0 h1; stage A_k0(t+1)
        if (st) {
            __builtin_amdgcn_global_load_lds(AS1(gA[0] + koff), AS3(pt +    0 + ldst), 16, 0, 0);
            __builtin_amdgcn_global_load_lds(AS1(gA[1] + koff), AS3(pt + 8192 + ldst), 16, 0, 0);
        }
        __builtin_amdgcn_s_barrier();    // no compiler fence: reads of pb may float
        #pragma unroll
        for (int f = 0; f < 4; ++f)
            afB[f] = *(const bf16x8*)(pb + 4096 + aoff + f * 1024);
        MFMA16(afA, bv0, 0)

        // ---- ph1: MFMA(afB,bv0)->acc[4..7]; read afA <- A_k1 h0, bv1 <- B_k1; stage B_k0(t+1)
        if (st) {
            __builtin_amdgcn_global_load_lds(AS1(gB[0] + koff), AS3(pt + 32768 + ldst), 16, 0, 0);
            __builtin_amdgcn_global_load_lds(AS1(gB[1] + koff), AS3(pt + 40960 + ldst), 16, 0, 0);
            asm volatile("s_waitcnt vmcnt(4)" ::: "memory");   // GATE: retires A_k1(t),B_k1(t)
        } else {
            asm volatile("s_waitcnt vmcnt(0)" ::: "memory");
        }
        __builtin_amdgcn_s_barrier();
        #pragma unroll
        for (int f = 0; f < 4; ++f) {
            afA[f] = *(const bf16x8*)(pb + 16384 + aoff + f * 1024);   // A_k1 h0
            bv1[f] = *(const bf16x8*)(pb + 49152 + boff + f * 1024);   // B_k1
        }
        MFMA16(afB, bv0, 1)

        // ---- ph2: MFMA(afA,bv1)->acc[0..3]; read afB <- A_k1 h1; stage A_k1(t+1)
        if (st) {
            __builtin_amdgcn_global_load_lds(AS1(gA[0] + koff + 64), AS3(pt + 16384 + ldst), 16, 0, 0);
            __builtin_amdgcn_global_load_lds(AS1(gA[1] + koff + 64), AS3(pt + 24576 + ldst), 16, 0, 0);
        }
        __builtin_amdgcn_s_barrier();
        #pragma unroll
        for (int f = 0; f < 4; ++f)
            afB[f] = *(const bf16x8*)(pb + 16384 + 4096 + aoff + f * 1024);
        MFMA16(afA, bv1, 0)

        // ---- ph3: MFMA(afB,bv1)->acc[4..7]; read afA,bv0 <- NEXT tile (from pt); stage B_k1(t+1)
        if (st) {
            __builtin_amdgcn_global_load_lds(AS1(gB[0] + koff + 64), AS3(pt + 49152 + ldst), 16, 0, 0);
            __builtin_amdgcn_global_load_lds(AS1(gB[1] + koff + 64), AS3(pt + 57344 + ldst), 16, 0, 0);
            asm volatile("s_waitcnt vmcnt(4)" ::: "memory");   // GATE: retires A_k0(t+1),B_k0(t+1)
        }
        __builtin_amdgcn_s_barrier();
        if (st) {
            #pragma unroll
            for (int f = 0; f < 4; ++f) {
                afA[f] = *(const bf16x8*)(pt +     0 + aoff + f * 1024);   // A_k0(t+1) h0
                bv0[f] = *(const bf16x8*)(pt + 32768 + boff + f * 1024);   // B_k0(t+1)
            }
        }
        MFMA16(afB, bv1, 1)
    }
#undef MFMA16

    // epilogue: row = row0 + wm*128 + i*16 + (lane>>4)*4 + e ; col = col0 + wn*64 + j*16 + r16
    const int rb = (lane >> 4) * 4;
    #pragma unroll
    for (int i = 0; i < 8; ++i) {
        #pragma unroll
        for (int j = 0; j < 4; ++j) {
            const int cc = col0 + wn * 64 + j * 16 + r16;
            float badd = 0.f;
            if (MODE == 1) badd = bias[cc];
            #pragma unroll
            for (int e = 0; e < 4; ++e) {
                long row = row0 + wm * 128 + i * 16 + rb + e;
                float v = acc[i][j][e];
                if (MODE == 1) {
                    v += badd;
                    v = fmaxf(v, 0.f);
                    v = v * v;
                    ((bf16*)Cout)[row * ldc + cc] = __float2bfloat16(v);
                } else {
                    ((float*)Cout)[row * ldc + cc] = v;
                }
            }
        }
    }
}

// ---------------- glue: per-token gating / tiny einsums ----------------
// In:  g1,g2 [TOK][8][512] f32; Yl[:,0:4096]=x1 raw bf16; Yr[:,4096:8192]=x2 raw bf16
// Out: Yl = [x1*g1s | y12 | g1s]; Yr = [y21 | x2*g2s | g2s]  (all bf16)
#define GPAD 524   // 8-row pad: h-stride hits 8 distinct banks; 524*4%16==0
__global__ __launch_bounds__(256)
void glue(const float* __restrict__ g1, const float* __restrict__ g2,
          bf16* __restrict__ Yl, bf16* __restrict__ Yr)
{
    __shared__ __align__(16) float g1t[8 * GPAD];
    __shared__ __align__(16) float g2t[8 * GPAD];
    __shared__ float g1s[EE], g2s[EE];
    __shared__ float t1s[64], t2s[64];
    __shared__ float t1p[4][64], t2p[4][64];
    __shared__ __align__(16) bf16 x1t[FF], x2t[FF];

    const int t   = blockIdx.x;
    const int tid = threadIdx.x;
    const float* g1p = g1 + (size_t)t * FF;
    const float* g2p = g2 + (size_t)t * FF;
    bf16* ylp = Yl + (size_t)t * KCAT;
    bf16* yrp = Yr + (size_t)t * KCAT;

    #pragma unroll
    for (int c = 0; c < 4; ++c) {
        int idx4 = (c * 256 + tid) * 4;
        float4 v1 = *(const float4*)(g1p + idx4);
        float4 v2 = *(const float4*)(g2p + idx4);
        int h = idx4 >> 9, e = idx4 & 511;
        *(float4*)&g1t[h * GPAD + e] = v1;
        *(float4*)&g2t[h * GPAD + e] = v2;
    }
    #pragma unroll
    for (int c = 0; c < 2; ++c) {
        int idx8 = (c * 256 + tid) * 8;
        *(bf16x8*)&x1t[idx8] = *(const bf16x8*)(ylp + idx8);
        *(bf16x8*)&x2t[idx8] = *(const bf16x8*)(yrp + FF + idx8);
    }
    __syncthreads();

    #pragma unroll
    for (int c = 0; c < 2; ++c) {
        int e = c * 256 + tid;
        float s1 = 0.f, s2 = 0.f;
        #pragma unroll
        for (int h = 0; h < 8; ++h) { s1 += g1t[h * GPAD + e]; s2 += g2t[h * GPAD + e]; }
        g1s[e] = s1; g2s[e] = s2;
    }

    {   // t1[h,m] = sum_e x1[e,m]*g1[h,e] ; t2 likewise. 4-way partials.
        int o = tid & 63;
        int h = o & 7, m = o >> 3;
        int p = tid >> 6;
        float s1 = 0.f, s2 = 0.f;
        #pragma unroll 8
        for (int ii = 0; ii < 128; ++ii) {
            int e = p * 128 + ii;
            float xv1 = __bfloat162float(x1t[e * 8 + m]);
            float xv2 = __bfloat162float(x2t[e * 8 + m]);
            s1 += xv1 * g1t[h * GPAD + e];
            s2 += xv2 * g2t[h * GPAD + e];
        }
        t1p[p][o] = s1; t2p[p][o] = s2;
    }
    __syncthreads();
    if (tid < 64)       t1s[tid] = t1p[0][tid] + t1p[1][tid] + t1p[2][tid] + t1p[3][tid];
    else if (tid < 128) { int o = tid - 64; t2s[o] = t2p[0][o] + t2p[1][o] + t2p[2][o] + t2p[3][o]; }
    __syncthreads();

    #pragma unroll
    for (int c = 0; c < 2; ++c) {
        int f0 = (c * 256 + tid) * 8;
        int e  = f0 >> 3;
        float s1 = g1s[e], s2 = g2s[e];
        bf16x8 xa = *(const bf16x8*)&x1t[f0];
        bf16x8 xb = *(const bf16x8*)&x2t[f0];
        bf16x8 o1, o2;
        #pragma unroll
        for (int u = 0; u < 8; ++u) {
            o1[u] = (__bf16)((float)xa[u] * s1);
            o2[u] = (__bf16)((float)xb[u] * s2);
        }
        *(bf16x8*)(ylp + f0)      = o1;
        *(bf16x8*)(yrp + FF + f0) = o2;
    }
    #pragma unroll
    for (int c = 0; c < 2; ++c) {
        int f0 = (c * 256 + tid) * 8;
        int i  = f0 >> 3;
        bf16x8 o12v, o21v;
        #pragma unroll
        for (int m = 0; m < 8; ++m) {
            float s12 = 0.f, s21 = 0.f;
            #pragma unroll
            for (int h = 0; h < 8; ++h) {
                s12 += t2s[(m << 3) | h] * g1t[h * GPAD + i];
                s21 += t1s[(m << 3) | h] * g2t[h * GPAD + i];
            }
            o12v[m] = (__bf16)s12;
            o21v[m] = (__bf16)s21;
        }
        *(bf16x8*)(ylp + FF + f0) = o12v;
        *(bf16x8*)(yrp + f0)      = o21v;
    }
    {
        int e0 = tid * 2;
        ylp[2 * FF + e0]     = __float2bfloat16(g1s[e0]);
        ylp[2 * FF + e0 + 1] = __float2bfloat16(g1s[e0 + 1]);
        yrp[2 * FF + e0]     = __float2bfloat16(g2s[e0]);
        yrp[2 * FF + e0 + 1] = __float2bfloat16(g2s[e0 + 1]);
    }
}

// ---------------- launch ----------------

extern "C" void kernel_launch(void* const* d_in, const int* in_sizes, int n_in,
                              void* d_out, int out_size, void* d_ws, size_t ws_size,
                              hipStream_t stream) {
    const float* x    = (const float*)d_in[0];
    const float* g1   = (const float*)d_in[1];
    const float* g2   = (const float*)d_in[2];
    const float* u1_w = (const float*)d_in[3];
    const float* u1_b = (const float*)d_in[4];
    const float* u2_w = (const float*)d_in[5];
    const float* u2_b = (const float*)d_in[6];
    const float* v11  = (const float*)d_in[7];
    const float* v12  = (const float*)d_in[8];
    const float* v21  = (const float*)d_in[9];
    const float* v22  = (const float*)d_in[10];
    const float* b1   = (const float*)d_in[11];
    const float* b2   = (const float*)d_in[12];
    float* out = (float*)d_out;

    size_t off = 0;
    char* base = (char*)d_ws;
    auto take = [&](size_t bytes) { void* p = base + off; off += (bytes + 255) & ~(size_t)255; return p; };
    bf16* Xb  = (bf16*)take((size_t)TOK * DD * 2);
    bf16* U1b = (bf16*)take((size_t)FF * DD * 2);
    bf16* U2b = (bf16*)take((size_t)FF * DD * 2);
    bf16* Wl  = (bf16*)take((size_t)HALF * KCAT * 2);
    bf16* Wr  = (bf16*)take((size_t)HALF * KCAT * 2);
    bf16* Yl  = (bf16*)take((size_t)TOK * KCAT * 2);
    bf16* Yr  = (bf16*)take((size_t)TOK * KCAT * 2);

    // prep: x/u casts only (v/b packing rides inside the U-GEMM launch)
    prep_cvt<<<2048, 256, 0, stream>>>(x, u1_w, u2_w, Xb, U1b, U2b);

    // fused U-GEMMs (+256 piggyback pack blocks): x1raw -> Yl[:,0:4096],
    // x2raw -> Yr[:,4096:8192] (relu^2, bf16); v/b -> Wl/Wr
    gemmP<1><<<2 * (TOK / 256) * (FF / 256) + 256, 512, 0, stream>>>(
        Xb, U1b, u1_b, Yl,
        Xb, U2b, u2_b, Yr + FF,
        TOK / 256, FF / 256, DD, KCAT,
        v11, v12, v21, v22, b1, b2, Wl, Wr);

    // gating / tiny einsums
    glue<<<TOK, 256, 0, stream>>>(g1, g2, Yl, Yr);

    // fused V-GEMMs: out[:,0:1024] = Yl @ Wl^T ; out[:,1024:2048] = Yr @ Wr^T  (fp32)
    gemmP<0><<<2 * (TOK / 256) * (HALF / 256), 512, 0, stream>>>(
        Yl, Wl, nullptr, out,
        Yr, Wr, nullptr, out + HALF,
        TOK / 256, HALF / 256, KCAT, DD,
        nullptr, nullptr, nullptr, nullptr, nullptr, nullptr, nullptr, nullptr);
}